// Round 1
// baseline (1839.133 us; speedup 1.0000x reference)
//
#include <hip/hip_runtime.h>
#include <math.h>

// AFNO block: LN -> rfft2 -> per-mode block-diag complex matmul + ReLU -> irfft2
//             -> LN -> MLP(GELU) -> xs + residual + mlp_out
// All fp32. DIM=384, H=W=64, NB=8, BS=48, WF=33, B=8.

#define BB 8
#define HH 64
#define WW 64
#define CC 384
#define WF 33
#define NBK 8
#define BSZ 48
#define NTOK (BB*HH*WW)   // 32768
#define TW64 0.09817477042468103f  // 2*pi/64

// ---------------- LayerNorm (one token per wave, 4 tokens per 256-thr block) ----
__global__ __launch_bounds__(256) void ln_kernel(const float* __restrict__ in,
    const float* __restrict__ g, const float* __restrict__ bsh, float* __restrict__ out) {
  int token = blockIdx.x * 4 + (threadIdx.x >> 6);
  int lane = threadIdx.x & 63;
  const float* row = in + (size_t)token * CC;
  float v[6]; float s = 0.f;
#pragma unroll
  for (int j = 0; j < 6; ++j) { v[j] = row[lane + 64*j]; s += v[j]; }
#pragma unroll
  for (int off = 32; off >= 1; off >>= 1) s += __shfl_xor(s, off);
  float mu = s * (1.0f/CC);
  float q = 0.f;
#pragma unroll
  for (int j = 0; j < 6; ++j) { float d = v[j] - mu; q += d*d; }
#pragma unroll
  for (int off = 32; off >= 1; off >>= 1) q += __shfl_xor(q, off);
  float rs = rsqrtf(q * (1.0f/CC) + 1e-5f);
  float* orow = out + (size_t)token * CC;
#pragma unroll
  for (int j = 0; j < 6; ++j) {
    int c = lane + 64*j;
    orow[c] = (v[j]-mu)*rs*g[c] + bsh[c];
  }
}

// ---------------- Stage A: rfft along W (64 real -> 33 complex), ortho 1/8 -----
// grid: B*H*2 (c split in halves of 192), block 384 (lane=c, tid/192 = kw parity)
__global__ __launch_bounds__(384) void rfft_w_kernel(const float* __restrict__ in,
                                                     float2* __restrict__ out) {
  int bid = blockIdx.x;
  int chalf = bid & 1;
  int bh = bid >> 1;                  // b*64+h
  int tid = threadIdx.x;
  int lane = tid % 192;
  int kwhalf = tid / 192;
  __shared__ float tile[64][192];
  __shared__ float twc[64], tws[64];
  if (tid < 64) { float th = tid * TW64; twc[tid] = cosf(th); tws[tid] = sinf(th); }
  const float* base = in + (size_t)bh * (WW*CC) + chalf*192;
  for (int idx = tid; idx < 64*192; idx += 384) {
    int w = idx / 192, l = idx % 192;
    tile[w][l] = base[(size_t)w*CC + l];
  }
  __syncthreads();
  float2* obase = out + (size_t)bh * (WF*CC) + chalf*192 + lane;
  for (int kw = kwhalf; kw <= 32; kw += 2) {
    float re = 0.f, im = 0.f;
#pragma unroll
    for (int w = 0; w < 64; ++w) {
      int t = (kw*w) & 63;
      float vv = tile[w][lane];
      re = fmaf(vv,  twc[t], re);
      im = fmaf(vv, -tws[t], im);
    }
    obase[(size_t)kw*CC] = make_float2(re*0.125f, im*0.125f);
  }
}

// ---------------- Stage B/C: complex DFT along H, sign=-1 fwd / +1 inv, ortho 1/8
// grid: B*WF*6 (c chunks of 64), block 256: lane=c, tid>>6 = kh group
__global__ __launch_bounds__(256) void fft_h_kernel(const float2* __restrict__ in,
                                                    float2* __restrict__ out, float sign) {
  int bid = blockIdx.x;
  int cchunk = bid % 6;
  int kw = (bid / 6) % WF;
  int b = bid / (6*WF);
  int tid = threadIdx.x;
  int lane = tid & 63;
  int grp = tid >> 6;
  __shared__ float2 tile[64][64];
  __shared__ float twc[64], tws[64];
  if (tid < 64) { float th = tid * TW64; twc[tid] = cosf(th); tws[tid] = sinf(th); }
  int c0 = cchunk*64;
  for (int idx = tid; idx < 64*64; idx += 256) {
    int h = idx >> 6, l = idx & 63;
    tile[h][l] = in[((size_t)(b*HH + h)*WF + kw)*CC + c0 + l];
  }
  __syncthreads();
  for (int kh = grp; kh < 64; kh += 4) {
    float re = 0.f, im = 0.f;
#pragma unroll
    for (int h = 0; h < 64; ++h) {
      int t = (kh*h) & 63;
      float2 vv = tile[h][lane];
      float cr = twc[t], ci = sign * tws[t];
      re += vv.x*cr - vv.y*ci;
      im += vv.x*ci + vv.y*cr;
    }
    out[((size_t)(b*HH + kh)*WF + kw)*CC + c0 + lane] = make_float2(re*0.125f, im*0.125f);
  }
}

// ---------------- Per-mode block-diagonal complex matmul + bias + split ReLU ----
// grid: H*WF*NB = 16896, block 384 = 8 batches x 48 outputs
__global__ __launch_bounds__(384) void blockmm_kernel(const float2* __restrict__ xf,
    const float* __restrict__ w1, const float* __restrict__ b1, float2* __restrict__ o1) {
  int bid = blockIdx.x;
  int n = bid % NBK;
  int kw = (bid / NBK) % WF;
  int h = bid / (NBK*WF);
  int tid = threadIdx.x;
  __shared__ float2 wl[BSZ*BSZ];   // [i][o]
  __shared__ float2 xl[BB][BSZ];
  __shared__ float2 bl[BSZ];
  const float2* wbase = (const float2*)w1 + ((size_t)(h*WF + kw)*NBK + n)*(BSZ*BSZ);
  for (int t = tid; t < BSZ*BSZ; t += 384) wl[t] = wbase[t];
  const float2* bbase = (const float2*)b1 + ((size_t)(h*WF + kw)*NBK + n)*BSZ;
  if (tid < BSZ) bl[tid] = bbase[tid];
  {
    int bb = tid / BSZ, i = tid % BSZ;
    xl[bb][i] = xf[((size_t)(bb*HH + h)*WF + kw)*CC + n*BSZ + i];
  }
  __syncthreads();
  int bb = tid / BSZ, o = tid % BSZ;
  float2 acc = bl[o];
#pragma unroll
  for (int i = 0; i < BSZ; ++i) {
    float2 xv = xl[bb][i];
    float2 wv = wl[i*BSZ + o];
    acc.x += xv.x*wv.x - xv.y*wv.y;
    acc.y += xv.x*wv.y + xv.y*wv.x;
  }
  acc.x = fmaxf(acc.x, 0.f);
  acc.y = fmaxf(acc.y, 0.f);
  o1[((size_t)(bb*HH + h)*WF + kw)*CC + n*BSZ + o] = acc;
}

// ---------------- Stage D: irfft along W (33 complex -> 64 real), ortho 1/8 -----
// Hermitian fold; imag of bins 0 and 32 ignored (pocketfft c2r semantics).
__global__ __launch_bounds__(384) void irfft_w_kernel(const float2* __restrict__ in,
                                                      float* __restrict__ out) {
  int bid = blockIdx.x;
  int chalf = bid & 1;
  int bh = bid >> 1;
  int tid = threadIdx.x;
  int lane = tid % 192;
  int whalf = tid / 192;
  __shared__ float2 tile[WF][192];
  __shared__ float twc[64], tws[64];
  if (tid < 64) { float th = tid * TW64; twc[tid] = cosf(th); tws[tid] = sinf(th); }
  const float2* base = in + (size_t)bh*(WF*CC) + chalf*192;
  for (int idx = tid; idx < WF*192; idx += 384) {
    int k = idx / 192, l = idx % 192;
    tile[k][l] = base[(size_t)k*CC + l];
  }
  __syncthreads();
  float* obase = out + (size_t)bh*(WW*CC) + chalf*192 + lane;
  float x0 = tile[0][lane].x;
  float x32 = tile[32][lane].x;
  for (int w = whalf; w < 64; w += 2) {
    float val = x0 + ((w & 1) ? -x32 : x32);
#pragma unroll
    for (int k = 1; k <= 31; ++k) {
      int t = (k*w) & 63;
      float2 vv = tile[k][lane];
      val += 2.f*(vv.x*twc[t] - vv.y*tws[t]);   // Re(X * e^{+i 2pi k w /64})
    }
    obase[(size_t)w*CC] = val*0.125f;
  }
}

// ---------------- out = xs + x + b2 ------------------------------------------
__global__ __launch_bounds__(256) void initout_kernel(const float* __restrict__ xs,
    const float* __restrict__ x, const float* __restrict__ b2, float* __restrict__ out) {
  int i = blockIdx.x*256 + threadIdx.x;
  out[i] = xs[i] + x[i] + b2[i % CC];
}

// ---------------- fp32 tiled GEMM, M=32768 N=384 K=384 ------------------------
// BM=BN=64, BK=16, 256 threads, 4x4 microtile. Optional bias+GELU, optional +=.
__global__ __launch_bounds__(256) void mlp_gemm_kernel(const float* __restrict__ A,
    const float* __restrict__ Bm, const float* __restrict__ bias, float* __restrict__ Cm,
    int ldb, int applyGelu, int accum) {
  __shared__ float As[16][68];
  __shared__ float Bs[16][68];
  int tid = threadIdx.x;
  int bm = blockIdx.x & 511;          // 32768/64 = 512
  int bn = blockIdx.x >> 9;           // 0..5
  int tx = tid & 15, ty = tid >> 4;
  float acc[4][4] = {};
  const float* Ab = A + (size_t)bm*64*CC;
  const float* Bb = Bm + bn*64;
  for (int kk = 0; kk < CC; kk += 16) {
#pragma unroll
    for (int l = 0; l < 4; ++l) {
      int idx = tid + l*256;
      int m = idx >> 4, k = idx & 15;
      As[k][m] = Ab[(size_t)m*CC + kk + k];
    }
#pragma unroll
    for (int l = 0; l < 4; ++l) {
      int idx = tid + l*256;
      int k = idx >> 6, nn = idx & 63;
      Bs[k][nn] = Bb[(size_t)(kk + k)*ldb + nn];
    }
    __syncthreads();
#pragma unroll
    for (int k = 0; k < 16; ++k) {
      float av[4], bv[4];
#pragma unroll
      for (int i2 = 0; i2 < 4; ++i2) av[i2] = As[k][ty*4 + i2];
#pragma unroll
      for (int j2 = 0; j2 < 4; ++j2) bv[j2] = Bs[k][tx*4 + j2];
#pragma unroll
      for (int i2 = 0; i2 < 4; ++i2)
#pragma unroll
        for (int j2 = 0; j2 < 4; ++j2) acc[i2][j2] = fmaf(av[i2], bv[j2], acc[i2][j2]);
    }
    __syncthreads();
  }
#pragma unroll
  for (int i2 = 0; i2 < 4; ++i2) {
    int m = bm*64 + ty*4 + i2;
#pragma unroll
    for (int j2 = 0; j2 < 4; ++j2) {
      int nloc = bn*64 + tx*4 + j2;
      float v = acc[i2][j2];
      if (bias) v += bias[nloc];
      if (applyGelu) v = 0.5f*v*(1.f + erff(v*0.70710678118654752f));
      size_t ci = (size_t)m*CC + nloc;
      if (accum) Cm[ci] += v; else Cm[ci] = v;
    }
  }
}

extern "C" void kernel_launch(void* const* d_in, const int* in_sizes, int n_in,
                              void* d_out, int out_size, void* d_ws, size_t ws_size,
                              hipStream_t stream) {
  const float* x   = (const float*)d_in[0];
  const float* w1  = (const float*)d_in[1];
  const float* b1  = (const float*)d_in[2];
  const float* n1w = (const float*)d_in[3];
  const float* n1b = (const float*)d_in[4];
  const float* n2w = (const float*)d_in[5];
  const float* n2b = (const float*)d_in[6];
  const float* mw1 = (const float*)d_in[7];
  const float* mb1 = (const float*)d_in[8];
  const float* mw2 = (const float*)d_in[9];
  const float* mb2 = (const float*)d_in[10];
  float* out = (float*)d_out;

  // workspace: two 52 MB regions (need >= ~104 MB)
  float* bufA = (float*)d_ws;
  float* bufB = (float*)((char*)d_ws + (size_t)54525952);

  // 1. LN1: x -> bufA (xn)
  ln_kernel<<<NTOK/4, 256, 0, stream>>>(x, n1w, n1b, bufA);
  // 2. rfft along W: bufA -> bufB (complex, [b][h][kw][c])
  rfft_w_kernel<<<BB*HH*2, 384, 0, stream>>>(bufA, (float2*)bufB);
  // 3. FFT along H (fwd): bufB -> bufA (xf)
  fft_h_kernel<<<BB*WF*6, 256, 0, stream>>>((const float2*)bufB, (float2*)bufA, -1.f);
  // 4. block matmul + bias + ReLU: bufA -> bufB (o1)
  blockmm_kernel<<<HH*WF*NBK, 384, 0, stream>>>((const float2*)bufA, w1, b1, (float2*)bufB);
  // 5. inverse FFT along H: bufB -> bufA
  fft_h_kernel<<<BB*WF*6, 256, 0, stream>>>((const float2*)bufB, (float2*)bufA, +1.f);
  // 6. irfft along W: bufA -> bufB (xs, real)
  irfft_w_kernel<<<BB*HH*2, 384, 0, stream>>>((const float2*)bufA, bufB);
  // 7. LN2: bufB(xs) -> bufA (xm)
  ln_kernel<<<NTOK/4, 256, 0, stream>>>(bufB, n2w, n2b, bufA);
  // 8. out = xs + x + b2
  initout_kernel<<<(NTOK*CC)/256, 256, 0, stream>>>(bufB, x, mb2, out);
  // 9. MLP in 4 hidden chunks of 384: bufB = gelu(xm @ W1_chunk + b1_chunk); out += bufB @ W2_chunk
  for (int cf = 0; cf < 4; ++cf) {
    mlp_gemm_kernel<<<512*6, 256, 0, stream>>>(bufA, mw1 + (size_t)cf*384, mb1 + (size_t)cf*384,
                                               bufB, 1536, 1, 0);
    mlp_gemm_kernel<<<512*6, 256, 0, stream>>>(bufB, mw2 + (size_t)cf*384*384, nullptr,
                                               out, 384, 0, 1);
  }
}

// Round 2
// 918.812 us; speedup vs baseline: 2.0016x; 2.0016x over previous
//
#include <hip/hip_runtime.h>
#include <math.h>

// AFNO block: LN -> rfft2 -> per-mode block-diag complex matmul + ReLU -> irfft2
//             -> LN -> MLP(GELU, bf16 MFMA) -> xs + residual + mlp_out
// DIM=384, H=W=64, NB=8, BS=48, WF=33, B=8.

#define BB 8
#define HH 64
#define WW 64
#define CC 384
#define WF 33
#define NBK 8
#define BSZ 48
#define NTOK (BB*HH*WW)   // 32768
#define TW64 0.09817477042468103f  // 2*pi/64

typedef __attribute__((ext_vector_type(8))) short bf16x8;
typedef __attribute__((ext_vector_type(4))) float f32x4;

__device__ __forceinline__ unsigned short f2b(float f) {
  union { float f; unsigned u; } x; x.f = f;
  unsigned u = x.u;
  return (unsigned short)((u + 0x7fffu + ((u >> 16) & 1u)) >> 16);
}

__device__ __forceinline__ void gload16(const void* g, void* l) {
  __builtin_amdgcn_global_load_lds(
      (const __attribute__((address_space(1))) void*)g,
      (__attribute__((address_space(3))) void*)l, 16, 0, 0);
}

// ---------------- LayerNorm (one token per wave, 4 tokens per 256-thr block) ----
template<int OUTBF16>
__global__ __launch_bounds__(256) void ln_kernel(const float* __restrict__ in,
    const float* __restrict__ g, const float* __restrict__ bsh, void* __restrict__ outp) {
  int token = blockIdx.x * 4 + (threadIdx.x >> 6);
  int lane = threadIdx.x & 63;
  const float* row = in + (size_t)token * CC;
  float v[6]; float s = 0.f;
#pragma unroll
  for (int j = 0; j < 6; ++j) { v[j] = row[lane + 64*j]; s += v[j]; }
#pragma unroll
  for (int off = 32; off >= 1; off >>= 1) s += __shfl_xor(s, off);
  float mu = s * (1.0f/CC);
  float q = 0.f;
#pragma unroll
  for (int j = 0; j < 6; ++j) { float d = v[j] - mu; q += d*d; }
#pragma unroll
  for (int off = 32; off >= 1; off >>= 1) q += __shfl_xor(q, off);
  float rs = rsqrtf(q * (1.0f/CC) + 1e-5f);
#pragma unroll
  for (int j = 0; j < 6; ++j) {
    int c = lane + 64*j;
    float val = (v[j]-mu)*rs*g[c] + bsh[c];
    if (OUTBF16) ((unsigned short*)outp)[(size_t)token*CC + c] = f2b(val);
    else         ((float*)outp)[(size_t)token*CC + c] = val;
  }
}

// ---------------- Stage A: rfft along W (64 real -> 33 complex), ortho 1/8 -----
__global__ __launch_bounds__(384) void rfft_w_kernel(const float* __restrict__ in,
                                                     float2* __restrict__ out) {
  int bid = blockIdx.x;
  int chalf = bid & 1;
  int bh = bid >> 1;                  // b*64+h
  int tid = threadIdx.x;
  int lane = tid % 192;
  int kwhalf = tid / 192;
  __shared__ float tile[64][192];
  __shared__ float twc[64], tws[64];
  if (tid < 64) { float th = tid * TW64; twc[tid] = cosf(th); tws[tid] = sinf(th); }
  const float* base = in + (size_t)bh * (WW*CC) + chalf*192;
  for (int idx = tid; idx < 64*192; idx += 384) {
    int w = idx / 192, l = idx % 192;
    tile[w][l] = base[(size_t)w*CC + l];
  }
  __syncthreads();
  float2* obase = out + (size_t)bh * (WF*CC) + chalf*192 + lane;
  for (int kw = kwhalf; kw <= 32; kw += 2) {
    float re = 0.f, im = 0.f;
#pragma unroll
    for (int w = 0; w < 64; ++w) {
      int t = (kw*w) & 63;
      float vv = tile[w][lane];
      re = fmaf(vv,  twc[t], re);
      im = fmaf(vv, -tws[t], im);
    }
    obase[(size_t)kw*CC] = make_float2(re*0.125f, im*0.125f);
  }
}

// ---------------- Stage B/C: complex DFT along H, sign=-1 fwd / +1 inv, ortho 1/8
__global__ __launch_bounds__(256) void fft_h_kernel(const float2* __restrict__ in,
                                                    float2* __restrict__ out, float sign) {
  int bid = blockIdx.x;
  int cchunk = bid % 6;
  int kw = (bid / 6) % WF;
  int b = bid / (6*WF);
  int tid = threadIdx.x;
  int lane = tid & 63;
  int grp = tid >> 6;
  __shared__ float2 tile[64][64];
  __shared__ float twc[64], tws[64];
  if (tid < 64) { float th = tid * TW64; twc[tid] = cosf(th); tws[tid] = sinf(th); }
  int c0 = cchunk*64;
  for (int idx = tid; idx < 64*64; idx += 256) {
    int h = idx >> 6, l = idx & 63;
    tile[h][l] = in[((size_t)(b*HH + h)*WF + kw)*CC + c0 + l];
  }
  __syncthreads();
  for (int kh = grp; kh < 64; kh += 4) {
    float re = 0.f, im = 0.f;
#pragma unroll
    for (int h = 0; h < 64; ++h) {
      int t = (kh*h) & 63;
      float2 vv = tile[h][lane];
      float cr = twc[t], ci = sign * tws[t];
      re += vv.x*cr - vv.y*ci;
      im += vv.x*ci + vv.y*cr;
    }
    out[((size_t)(b*HH + kh)*WF + kw)*CC + c0 + lane] = make_float2(re*0.125f, im*0.125f);
  }
}

// ---------------- Per-mode block-diagonal complex matmul + bias + split ReLU ----
__global__ __launch_bounds__(384) void blockmm_kernel(const float2* __restrict__ xf,
    const float* __restrict__ w1, const float* __restrict__ b1, float2* __restrict__ o1) {
  int bid = blockIdx.x;
  int n = bid % NBK;
  int kw = (bid / NBK) % WF;
  int h = bid / (NBK*WF);
  int tid = threadIdx.x;
  __shared__ float2 wl[BSZ*BSZ];   // [i][o]
  __shared__ float2 xl[BB][BSZ];
  __shared__ float2 bl[BSZ];
  const float2* wbase = (const float2*)w1 + ((size_t)(h*WF + kw)*NBK + n)*(BSZ*BSZ);
  for (int t = tid; t < BSZ*BSZ; t += 384) wl[t] = wbase[t];
  const float2* bbase = (const float2*)b1 + ((size_t)(h*WF + kw)*NBK + n)*BSZ;
  if (tid < BSZ) bl[tid] = bbase[tid];
  {
    int bb = tid / BSZ, i = tid % BSZ;
    xl[bb][i] = xf[((size_t)(bb*HH + h)*WF + kw)*CC + n*BSZ + i];
  }
  __syncthreads();
  int bb = tid / BSZ, o = tid % BSZ;
  float2 acc = bl[o];
#pragma unroll
  for (int i = 0; i < BSZ; ++i) {
    float2 xv = xl[bb][i];
    float2 wv = wl[i*BSZ + o];
    acc.x += xv.x*wv.x - xv.y*wv.y;
    acc.y += xv.x*wv.y + xv.y*wv.x;
  }
  acc.x = fmaxf(acc.x, 0.f);
  acc.y = fmaxf(acc.y, 0.f);
  o1[((size_t)(bb*HH + h)*WF + kw)*CC + n*BSZ + o] = acc;
}

// ---------------- Stage D: irfft along W (33 complex -> 64 real), ortho 1/8 -----
__global__ __launch_bounds__(384) void irfft_w_kernel(const float2* __restrict__ in,
                                                      float* __restrict__ out) {
  int bid = blockIdx.x;
  int chalf = bid & 1;
  int bh = bid >> 1;
  int tid = threadIdx.x;
  int lane = tid % 192;
  int whalf = tid / 192;
  __shared__ float2 tile[WF][192];
  __shared__ float twc[64], tws[64];
  if (tid < 64) { float th = tid * TW64; twc[tid] = cosf(th); tws[tid] = sinf(th); }
  const float2* base = in + (size_t)bh*(WF*CC) + chalf*192;
  for (int idx = tid; idx < WF*192; idx += 384) {
    int k = idx / 192, l = idx % 192;
    tile[k][l] = base[(size_t)k*CC + l];
  }
  __syncthreads();
  float* obase = out + (size_t)bh*(WW*CC) + chalf*192 + lane;
  float x0 = tile[0][lane].x;
  float x32 = tile[32][lane].x;
  for (int w = whalf; w < 64; w += 2) {
    float val = x0 + ((w & 1) ? -x32 : x32);
#pragma unroll
    for (int k = 1; k <= 31; ++k) {
      int t = (k*w) & 63;
      float2 vv = tile[k][lane];
      val += 2.f*(vv.x*twc[t] - vv.y*tws[t]);
    }
    obase[(size_t)w*CC] = val*0.125f;
  }
}

// ---------------- out = xs + x + b2 ------------------------------------------
__global__ __launch_bounds__(256) void initout_kernel(const float* __restrict__ xs,
    const float* __restrict__ x, const float* __restrict__ b2, float* __restrict__ out) {
  int i = blockIdx.x*256 + threadIdx.x;
  out[i] = xs[i] + x[i] + b2[i % CC];
}

// ---------------- transpose + fp32->bf16 convert (weights) --------------------
// out[c*R + r] = bf16(in[r*C + c]); 32x32 LDS tiles, 256 threads
__global__ __launch_bounds__(256) void convtr_kernel(const float* __restrict__ in,
    unsigned short* __restrict__ out, int R, int C) {
  __shared__ float tile[32][33];
  int ntc = C >> 5;
  int bx = blockIdx.x % ntc;   // col tile
  int by = blockIdx.x / ntc;   // row tile
  int tx = threadIdx.x & 31, ty = threadIdx.x >> 5;
  for (int rr = ty; rr < 32; rr += 8)
    tile[rr][tx] = in[(size_t)(by*32+rr)*C + bx*32 + tx];
  __syncthreads();
  for (int rr = ty; rr < 32; rr += 8)
    out[(size_t)(bx*32+rr)*R + by*32 + tx] = f2b(tile[tx][rr]);
}

// ---------------- bf16 MFMA GEMM: C[MxN] = A[MxK] * BT[NxK]^T ------------------
// 128x128 tile, 4 waves (2x2), each wave 64x64 = 4x4 frags of 16x16x32 MFMA.
// BK=32, single-buffer LDS, 2-barrier loop, global_load_lds width-16 staging.
// GELU: epilogue v = gelu(v + bias[col]); OUTBF16: store bf16, else fp32 +=.
template<int GELU, int OUTBF16>
__global__ __launch_bounds__(256) void mfma_gemm_kernel(
    const unsigned short* __restrict__ A, int lda,
    const unsigned short* __restrict__ BT, int ldbt,
    const float* __restrict__ bias,
    void* __restrict__ Cp, int ldc, int K, int mtiles) {
  __shared__ unsigned short As[128*32];  // [row][k] 8KB
  __shared__ unsigned short Bs[128*32];  // [n][k]   8KB
  int bm = blockIdx.x % mtiles;
  int bn = blockIdx.x / mtiles;
  int t = threadIdx.x;
  int lane = t & 63;
  int wid = t >> 6;
  int wm = wid >> 1, wn = wid & 1;

  f32x4 acc[4][4];
#pragma unroll
  for (int m = 0; m < 4; ++m)
#pragma unroll
    for (int n = 0; n < 4; ++n) acc[m][n] = (f32x4){0.f,0.f,0.f,0.f};

  const unsigned short* Abase = A + (size_t)bm*128*lda;
  const unsigned short* Bbase = BT + (size_t)bn*128*ldbt;
  int rr = lane & 15;
  int kg = (lane >> 4) * 8;

  for (int k0 = 0; k0 < K; k0 += 32) {
    // stage 128x32 of A and BT (byte index i = r*4096 + t*16)
#pragma unroll
    for (int r = 0; r < 2; ++r) {
      int i = r*4096 + t*16;
      int row = i >> 6;            // 64 B per row (32 bf16)
      int kc = (i & 63) >> 1;      // element offset within row
      gload16(Abase + (size_t)row*lda + k0 + kc, (char*)As + r*4096 + wid*1024);
      gload16(Bbase + (size_t)row*ldbt + k0 + kc, (char*)Bs + r*4096 + wid*1024);
    }
    __syncthreads();
    bf16x8 af[4], bfr[4];
#pragma unroll
    for (int m = 0; m < 4; ++m)
      af[m] = *(const bf16x8*)&As[(wm*64 + m*16 + rr)*32 + kg];
#pragma unroll
    for (int n = 0; n < 4; ++n)
      bfr[n] = *(const bf16x8*)&Bs[(wn*64 + n*16 + rr)*32 + kg];
#pragma unroll
    for (int m = 0; m < 4; ++m)
#pragma unroll
      for (int n = 0; n < 4; ++n)
        acc[m][n] = __builtin_amdgcn_mfma_f32_16x16x32_bf16(af[m], bfr[n], acc[m][n], 0, 0, 0);
    __syncthreads();
  }

  int rq = lane >> 4;
#pragma unroll
  for (int m = 0; m < 4; ++m) {
#pragma unroll
    for (int n = 0; n < 4; ++n) {
      int grow0 = bm*128 + wm*64 + m*16 + rq*4;
      int gcol  = bn*128 + wn*64 + n*16 + rr;
#pragma unroll
      for (int j = 0; j < 4; ++j) {
        float v = acc[m][n][j];
        if (GELU) { v += bias[gcol]; v = 0.5f*v*(1.f + erff(v*0.70710678118654752f)); }
        if (OUTBF16)
          ((unsigned short*)Cp)[(size_t)(grow0+j)*ldc + gcol] = f2b(v);
        else
          ((float*)Cp)[(size_t)(grow0+j)*ldc + gcol] += v;
      }
    }
  }
}

extern "C" void kernel_launch(void* const* d_in, const int* in_sizes, int n_in,
                              void* d_out, int out_size, void* d_ws, size_t ws_size,
                              hipStream_t stream) {
  const float* x   = (const float*)d_in[0];
  const float* w1  = (const float*)d_in[1];
  const float* b1  = (const float*)d_in[2];
  const float* n1w = (const float*)d_in[3];
  const float* n1b = (const float*)d_in[4];
  const float* n2w = (const float*)d_in[5];
  const float* n2b = (const float*)d_in[6];
  const float* mw1 = (const float*)d_in[7];
  const float* mb1 = (const float*)d_in[8];
  const float* mw2 = (const float*)d_in[9];
  const float* mb2 = (const float*)d_in[10];
  float* out = (float*)d_out;

  char* ws = (char*)d_ws;
  float* bufA = (float*)ws;                                  // 56 MB region
  float* bufB = (float*)(ws + (56ull << 20));                // 56 MB region
  unsigned short* xmb = (unsigned short*)(ws + (112ull << 20)); // 25 MB (LN2 bf16)
  unsigned short* w1t = (unsigned short*)(ws + (140ull << 20)); // [1536][384] bf16
  unsigned short* w2t = (unsigned short*)(ws + (144ull << 20)); // [384][1536] bf16
  unsigned short* hid = (unsigned short*)(ws + (148ull << 20)); // 100 MB bf16

  // weight convert+transpose (tiny)
  convtr_kernel<<<(384/32)*(1536/32), 256, 0, stream>>>(mw1, w1t, 384, 1536);
  convtr_kernel<<<(1536/32)*(384/32), 256, 0, stream>>>(mw2, w2t, 1536, 384);

  // 1. LN1: x -> bufA (fp32)
  ln_kernel<0><<<NTOK/4, 256, 0, stream>>>(x, n1w, n1b, bufA);
  // 2. rfft along W: bufA -> bufB
  rfft_w_kernel<<<BB*HH*2, 384, 0, stream>>>(bufA, (float2*)bufB);
  // 3. FFT along H (fwd): bufB -> bufA
  fft_h_kernel<<<BB*WF*6, 256, 0, stream>>>((const float2*)bufB, (float2*)bufA, -1.f);
  // 4. block matmul + bias + ReLU: bufA -> bufB
  blockmm_kernel<<<HH*WF*NBK, 384, 0, stream>>>((const float2*)bufA, w1, b1, (float2*)bufB);
  // 5. inverse FFT along H: bufB -> bufA
  fft_h_kernel<<<BB*WF*6, 256, 0, stream>>>((const float2*)bufB, (float2*)bufA, +1.f);
  // 6. irfft along W: bufA -> bufB (xs)
  irfft_w_kernel<<<BB*HH*2, 384, 0, stream>>>((const float2*)bufA, bufB);
  // 7. LN2: bufB -> xmb (bf16)
  ln_kernel<1><<<NTOK/4, 256, 0, stream>>>(bufB, n2w, n2b, xmb);
  // 8. out = xs + x + b2
  initout_kernel<<<(NTOK*CC)/256, 256, 0, stream>>>(bufB, x, mb2, out);
  // 9. GEMM1: hid = gelu(xm @ W1 + b1), bf16 out.  M=32768 N=1536 K=384
  mfma_gemm_kernel<1,1><<<256*12, 256, 0, stream>>>(xmb, 384, w1t, 384, mb1,
                                                    hid, 1536, 384, 256);
  // 10. GEMM2: out += hid @ W2.  M=32768 N=384 K=1536
  mfma_gemm_kernel<0,0><<<256*3, 256, 0, stream>>>(hid, 1536, w2t, 1536, nullptr,
                                                   out, 384, 1536, 256);
}

// Round 3
// 662.887 us; speedup vs baseline: 2.7744x; 1.3861x over previous
//
#include <hip/hip_runtime.h>
#include <math.h>

// AFNO block, MI355X. DFT stages as bf16-split MFMA GEMMs vs constant twiddle
// matrices; MLP as bf16 MFMA GEMMs; LN1 fused with transpose; residual+bias
// fused into W-inverse epilogue.

#define BB 8
#define HH 64
#define WW 64
#define CC 384
#define WF 33
#define NBK 8
#define BSZ 48
#define NTOK (BB*HH*WW)   // 32768
#define TW64 0.09817477042468103f  // 2*pi/64

typedef __attribute__((ext_vector_type(8))) short bf16x8;
typedef __attribute__((ext_vector_type(4))) float f32x4;

__device__ __forceinline__ unsigned short f2b(float f) {
  union { float f; unsigned u; } x; x.f = f;
  unsigned u = x.u;
  return (unsigned short)((u + 0x7fffu + ((u >> 16) & 1u)) >> 16);
}
__device__ __forceinline__ float b2fl(unsigned short u) {
  return __uint_as_float(((unsigned)u) << 16);
}
__device__ __forceinline__ void wr_split(unsigned short* ph, unsigned short* pl, float v) {
  unsigned short hv = f2b(v);
  *ph = hv;
  *pl = f2b(v - b2fl(hv));
}
__device__ __forceinline__ void gload16(const void* g, void* l) {
  __builtin_amdgcn_global_load_lds(
      (const __attribute__((address_space(1))) void*)g,
      (__attribute__((address_space(3))) void*)l, 16, 0, 0);
}

// ---------------- twiddle table init (bf16 hi/lo split) ------------------------
// elem offsets in A: awf_h 0, awf_l 5120, ahf_h 10240, ahf_l 26624,
//                    ahi_h 43008, ahi_l 59392, awi_h 75776, awi_l 79872
__global__ __launch_bounds__(256) void init_tw(unsigned short* __restrict__ A) {
  int idx0 = blockIdx.x * 256 + threadIdx.x;
  const float S = 0.125f;
  // AWf [80 m][64 w]: m=2kw+comp; comp0: cos/8, comp1: -sin/8 (0 for kw 0,32); m>=66 zero
  for (int e = idx0; e < 5120; e += 64*256) {
    int m = e >> 6, w = e & 63;
    float val = 0.f;
    if (m < 66) {
      int kwv = m >> 1;
      float th = (float)((kwv * w) & 63) * TW64;
      val = (m & 1) ? (((kwv==0)||(kwv==32)) ? 0.f : -sinf(th)*S) : cosf(th)*S;
    }
    wr_split(A + e, A + 5120 + e, val);
  }
  // AHf [comp_in 2][m'=(comp',kh) 128][h 64] (fwd: re=c*re+s*im; im=-s*re+c*im)
  for (int e = idx0; e < 16384; e += 64*256) {
    int comp = e >> 13; int r = e & 8191; int mp = r >> 6, hh = r & 63;
    int cpo = mp >> 6, kh = mp & 63;
    float th = (float)((kh * hh) & 63) * TW64;
    float cv = cosf(th), sv = sinf(th);
    float val = (cpo == 0) ? (comp == 0 ? cv : sv) : (comp == 0 ? -sv : cv);
    wr_split(A + 10240 + e, A + 26624 + e, val * S);
  }
  // AHi (inverse: re=c*re - s*im; im = s*re + c*im)
  for (int e = idx0; e < 16384; e += 64*256) {
    int comp = e >> 13; int r = e & 8191; int mp = r >> 6, hh = r & 63;
    int cpo = mp >> 6, kh = mp & 63;
    float th = (float)((kh * hh) & 63) * TW64;
    float cv = cosf(th), sv = sinf(th);
    float val = (cpo == 0) ? (comp == 0 ? cv : -sv) : (comp == 0 ? sv : cv);
    wr_split(A + 43008 + e, A + 59392 + e, val * S);
  }
  // AWi [w 64][kpack 64]: k<=32: cos*(k in {0,32}?1:2)/8; k>=33: -2 sin((k-32)w)/8
  for (int e = idx0; e < 4096; e += 64*256) {
    int w = e >> 6, kp = e & 63;
    float val;
    if (kp <= 32) {
      float th = (float)((kp * w) & 63) * TW64;
      val = cosf(th) * (((kp==0)||(kp==32)) ? 1.f : 2.f) * S;
    } else {
      int k2 = kp - 32;
      float th = (float)((k2 * w) & 63) * TW64;
      val = -2.f * sinf(th) * S;
    }
    wr_split(A + 75776 + e, A + 79872 + e, val);
  }
}

// ---------------- LN1 fused with transpose: x[b,h,w,c] -> xn[b,h,c,w] hi/lo ----
__global__ __launch_bounds__(256) void ln1t_kernel(const float* __restrict__ x,
    const float* __restrict__ g, const float* __restrict__ be,
    unsigned short* __restrict__ xh, unsigned short* __restrict__ xl) {
  int outer = blockIdx.x; int b = outer >> 6, h = outer & 63;
  int tid = threadIdx.x, lane = tid & 63, wg = tid >> 6;
  const float* base = x + ((size_t)(b*64 + h) * 64) * 384;  // [w][c]
  float s[16], s2[16];
#pragma unroll
  for (int q = 0; q < 16; ++q) { s[q] = 0.f; s2[q] = 0.f; }
  for (int ch = 0; ch < 6; ++ch) {
#pragma unroll
    for (int q = 0; q < 16; ++q) {
      float v = base[(size_t)(wg*16 + q)*384 + ch*64 + lane];
      s[q] += v; s2[q] += v*v;
    }
  }
#pragma unroll
  for (int q = 0; q < 16; ++q) {
#pragma unroll
    for (int off = 32; off >= 1; off >>= 1) {
      s[q] += __shfl_xor(s[q], off);
      s2[q] += __shfl_xor(s2[q], off);
    }
  }
  float mu[16], rs[16];
#pragma unroll
  for (int q = 0; q < 16; ++q) {
    mu[q] = s[q] * (1.f/384.f);
    rs[q] = rsqrtf(s2[q] * (1.f/384.f) - mu[q]*mu[q] + 1e-5f);
  }
  unsigned short* oh = xh + ((size_t)(b*64 + h) * 384) * 64;
  unsigned short* ol = xl + ((size_t)(b*64 + h) * 384) * 64;
  for (int ch = 0; ch < 6; ++ch) {
    int c = ch*64 + lane;
    float ga = g[c], bb2 = be[c];
#pragma unroll
    for (int qq = 0; qq < 4; ++qq) {
      unsigned hv[4], lv[4];
#pragma unroll
      for (int r2 = 0; r2 < 4; ++r2) {
        int q = qq*4 + r2;
        float v = base[(size_t)(wg*16 + q)*384 + c];
        float nv = (v - mu[q]) * rs[q] * ga + bb2;
        unsigned short hb = f2b(nv);
        hv[r2] = hb; lv[r2] = f2b(nv - b2fl(hb));
      }
      uint2 ph; ph.x = hv[0] | (hv[1] << 16); ph.y = hv[2] | (hv[3] << 16);
      uint2 pl; pl.x = lv[0] | (lv[1] << 16); pl.y = lv[2] | (lv[3] << 16);
      *(uint2*)(oh + (size_t)c*64 + wg*16 + qq*4) = ph;
      *(uint2*)(ol + (size_t)c*64 + wg*16 + qq*4) = pl;
    }
  }
}

// ---------------- DFT stage as MFMA GEMM ---------------------------------------
// STAGE: 0=W-fwd, 1=H-fwd, 2=H-inv, 3=W-inv(+residual fusion)
// C[M x 128c] = sum_seg A_seg[M x 64] * B_seg[64 x 128c]; hi/lo split = 3 terms.
template<int STAGE>
__global__ __launch_bounds__(256) void dft_kernel(
    const unsigned short* __restrict__ A0,
    const unsigned short* __restrict__ Dh, const unsigned short* __restrict__ Dl,
    unsigned short* __restrict__ Oh, unsigned short* __restrict__ Ol,
    const float* __restrict__ xres, const float* __restrict__ b2,
    float* __restrict__ xs, float* __restrict__ outp) {
  constexpr int M = (STAGE == 0) ? 80 : (STAGE == 3) ? 64 : 128;
  constexpr int MT = M / 16;
  __shared__ unsigned short Asm[M * 64];
  __shared__ unsigned short Bsm[128 * 64];
  int bid = blockIdx.x;
  int cc = bid % 3; int outer = bid / 3;
  int c0 = cc * 128;
  int tid = threadIdx.x, lane = tid & 63, wid = tid >> 6;
  int rr = lane & 15, rq = lane >> 4;
  int b, h = 0, kw = 0;
  if (STAGE == 0 || STAGE == 3) { b = outer >> 6; h = outer & 63; }
  else { b = outer / 33; kw = outer % 33; }

  f32x4 acc[MT][2];
#pragma unroll
  for (int mt = 0; mt < MT; ++mt)
#pragma unroll
    for (int nt = 0; nt < 2; ++nt) acc[mt][nt] = (f32x4){0.f,0.f,0.f,0.f};

  int nseg = (STAGE == 0 || STAGE == 3) ? 3
           : ((STAGE == 1 && (kw == 0 || kw == 32)) ? 3 : 6);

  for (int s = 0; s < nseg; ++s) {
    int term = (STAGE == 0 || STAGE == 3) ? s : s % 3;
    int comp = (STAGE == 0 || STAGE == 3) ? 0 : s / 3;
    const unsigned short* Asrc;
    if (STAGE == 0)      Asrc = A0 + (term < 2 ? 0     : 5120);
    else if (STAGE == 1) Asrc = A0 + (term < 2 ? 10240 : 26624) + comp * 8192;
    else if (STAGE == 2) Asrc = A0 + (term < 2 ? 43008 : 59392) + comp * 8192;
    else                 Asrc = A0 + (term < 2 ? 75776 : 79872);
    const unsigned short* Bb = (term == 1) ? Dl : Dh;

    // stage A tile [M][64], gload_lds with 16B-XOR source pre-swizzle
#pragma unroll
    for (int i = 0; i < (M*8 + 255)/256; ++i) {
      int t = tid + i*256;
      if (t < M*8) {
        int m = t >> 3, blk = t & 7;
        gload16(Asrc + m*64 + ((blk ^ (m & 7)) << 3),
                (char*)Asm + i*4096 + wid*1024);
      }
    }
    // stage B tile [c 128][k 64]
    if (STAGE == 0) {
      // xn[b,h,c,w]: k(w)-contiguous rows -> gload direct + source swizzle
      size_t PB = ((size_t)(b*64 + h)*384 + c0) * 64;
#pragma unroll
      for (int i = 0; i < 4; ++i) {
        int t = tid + i*256;
        int c = t >> 3, blk = t & 7;
        gload16(Bb + PB + (size_t)c*64 + ((blk ^ (c & 7)) << 3),
                (char*)Bsm + i*4096 + wid*1024);
      }
    } else {
      // c-contiguous rows -> pack4 transpose staging (coalesced u16 loads)
      size_t P; int RS;
      if (STAGE == 1) { P = (size_t)b*(64*66*384) + (size_t)(2*kw + comp)*384 + c0; RS = 66*384; }
      else if (STAGE == 2) { P = ((size_t)((b*2 + comp)*33) + kw)*64*384 + c0; RS = 384; }
      else { P = (size_t)b*(64*64*384) + (size_t)h*384 + c0; RS = 64*384; }
      const unsigned short* p0 = Bb + P;
#pragma unroll
      for (int i = 0; i < 8; ++i) {
        int t = tid + i*256;
        int kq = t >> 7, c = t & 127;
        const unsigned short* p = p0 + (size_t)(4*kq)*RS + c;
        unsigned u0 = p[0], u1 = p[RS], u2 = p[2*(size_t)RS], u3 = p[3*(size_t)RS];
        uint2 wv; wv.x = u0 | (u1 << 16); wv.y = u2 | (u3 << 16);
        int byteo = c*128 + ((kq*8) ^ ((c & 7) << 4));
        *(uint2*)((char*)Bsm + byteo) = wv;
      }
    }
    __syncthreads();
#pragma unroll
    for (int kh2 = 0; kh2 < 2; ++kh2) {
      int kb = kh2*64 + rq*16;
      bf16x8 bfr[2];
#pragma unroll
      for (int nt = 0; nt < 2; ++nt) {
        int n = wid*32 + nt*16 + rr;
        bfr[nt] = *(const bf16x8*)((const char*)Bsm + n*128 + (kb ^ ((n & 7) << 4)));
      }
#pragma unroll
      for (int mt = 0; mt < MT; ++mt) {
        int mr = mt*16 + rr;
        bf16x8 af = *(const bf16x8*)((const char*)Asm + mr*128 + (kb ^ ((mr & 7) << 4)));
#pragma unroll
        for (int nt = 0; nt < 2; ++nt)
          acc[mt][nt] = __builtin_amdgcn_mfma_f32_16x16x32_bf16(af, bfr[nt], acc[mt][nt], 0, 0, 0);
      }
    }
    __syncthreads();
  }

  // epilogue
#pragma unroll
  for (int mt = 0; mt < MT; ++mt) {
#pragma unroll
    for (int nt = 0; nt < 2; ++nt) {
#pragma unroll
      for (int j = 0; j < 4; ++j) {
        float v = acc[mt][nt][j];
        int m = mt*16 + rq*4 + j;
        int c = c0 + wid*32 + nt*16 + rr;
        if (STAGE == 0) {
          if (m < 66) {
            size_t idx = ((size_t)(b*64 + h)*66 + m)*384 + c;
            unsigned short hv = f2b(v);
            Oh[idx] = hv; Ol[idx] = f2b(v - b2fl(hv));
          }
        } else if (STAGE == 1) {
          int cp = m >> 6, kh = m & 63;
          size_t idx = (((size_t)((b*2 + cp)*64 + kh)*33) + kw)*384 + c;
          unsigned short hv = f2b(v);
          Oh[idx] = hv; Ol[idx] = f2b(v - b2fl(hv));
        } else if (STAGE == 2) {
          int cp = m >> 6, h2 = m & 63;
          if (!(cp == 1 && (kw == 0 || kw == 32))) {
            int kp = cp ? 32 + kw : kw;
            size_t idx = (((size_t)(b*64 + kp))*64 + h2)*384 + c;
            unsigned short hv = f2b(v);
            Oh[idx] = hv; Ol[idx] = f2b(v - b2fl(hv));
          }
        } else {
          size_t idx = (((size_t)(b*64 + h))*64 + m)*384 + c;
          xs[idx] = v;
          outp[idx] = v + xres[idx] + b2[c];
        }
      }
    }
  }
}

// ---------------- per-mode block-diag complex matmul + bias + split ReLU -------
__global__ __launch_bounds__(384) void blockmm2_kernel(
    const unsigned short* __restrict__ S2h, const unsigned short* __restrict__ S2l,
    const float* __restrict__ w1, const float* __restrict__ b1,
    unsigned short* __restrict__ o1h, unsigned short* __restrict__ o1l) {
  int bid = blockIdx.x;
  int n = bid % NBK;
  int kw = (bid / NBK) % WF;
  int h = bid / (NBK*WF);
  int tid = threadIdx.x;
  __shared__ float2 wl[BSZ*BSZ];
  __shared__ float2 xl2[BB][BSZ];
  __shared__ float2 bl[BSZ];
  const float2* wbase = (const float2*)w1 + ((size_t)(h*WF + kw)*NBK + n)*(BSZ*BSZ);
  for (int t = tid; t < BSZ*BSZ; t += 384) wl[t] = wbase[t];
  const float2* bbase = (const float2*)b1 + ((size_t)(h*WF + kw)*NBK + n)*BSZ;
  if (tid < BSZ) bl[tid] = bbase[tid];
  {
    int bb = tid / BSZ, i = tid % BSZ;
    size_t ir = (((size_t)((bb*2 + 0)*64 + h)*33) + kw)*384 + n*48 + i;
    size_t ii = (((size_t)((bb*2 + 1)*64 + h)*33) + kw)*384 + n*48 + i;
    float re = b2fl(S2h[ir]) + b2fl(S2l[ir]);
    float im = b2fl(S2h[ii]) + b2fl(S2l[ii]);
    xl2[bb][i] = make_float2(re, im);
  }
  __syncthreads();
  int bb = tid / BSZ, o = tid % BSZ;
  float2 acc = bl[o];
#pragma unroll
  for (int i = 0; i < BSZ; ++i) {
    float2 xv = xl2[bb][i];
    float2 wv = wl[i*BSZ + o];
    acc.x += xv.x*wv.x - xv.y*wv.y;
    acc.y += xv.x*wv.y + xv.y*wv.x;
  }
  acc.x = fmaxf(acc.x, 0.f);
  acc.y = fmaxf(acc.y, 0.f);
  size_t idr = (((size_t)((bb*2 + 0)*33) + kw)*64 + h)*384 + n*48 + o;
  size_t idi = (((size_t)((bb*2 + 1)*33) + kw)*64 + h)*384 + n*48 + o;
  unsigned short hr = f2b(acc.x);
  o1h[idr] = hr; o1l[idr] = f2b(acc.x - b2fl(hr));
  unsigned short hi2 = f2b(acc.y);
  o1h[idi] = hi2; o1l[idi] = f2b(acc.y - b2fl(hi2));
}

// ---------------- LayerNorm (fp32 in, bf16 or fp32 out) ------------------------
template<int OUTBF16>
__global__ __launch_bounds__(256) void ln_kernel(const float* __restrict__ in,
    const float* __restrict__ g, const float* __restrict__ bsh, void* __restrict__ outp) {
  int token = blockIdx.x * 4 + (threadIdx.x >> 6);
  int lane = threadIdx.x & 63;
  const float* row = in + (size_t)token * CC;
  float v[6]; float s = 0.f;
#pragma unroll
  for (int j = 0; j < 6; ++j) { v[j] = row[lane + 64*j]; s += v[j]; }
#pragma unroll
  for (int off = 32; off >= 1; off >>= 1) s += __shfl_xor(s, off);
  float mu = s * (1.0f/CC);
  float q = 0.f;
#pragma unroll
  for (int j = 0; j < 6; ++j) { float d = v[j] - mu; q += d*d; }
#pragma unroll
  for (int off = 32; off >= 1; off >>= 1) q += __shfl_xor(q, off);
  float rs = rsqrtf(q * (1.0f/CC) + 1e-5f);
#pragma unroll
  for (int j = 0; j < 6; ++j) {
    int c = lane + 64*j;
    float val = (v[j]-mu)*rs*g[c] + bsh[c];
    if (OUTBF16) ((unsigned short*)outp)[(size_t)token*CC + c] = f2b(val);
    else         ((float*)outp)[(size_t)token*CC + c] = val;
  }
}

// ---------------- transpose + fp32->bf16 convert (weights) ---------------------
__global__ __launch_bounds__(256) void convtr_kernel(const float* __restrict__ in,
    unsigned short* __restrict__ out, int R, int C) {
  __shared__ float tile[32][33];
  int ntc = C >> 5;
  int bx = blockIdx.x % ntc;
  int by = blockIdx.x / ntc;
  int tx = threadIdx.x & 31, ty = threadIdx.x >> 5;
  for (int rr2 = ty; rr2 < 32; rr2 += 8)
    tile[rr2][tx] = in[(size_t)(by*32+rr2)*C + bx*32 + tx];
  __syncthreads();
  for (int rr2 = ty; rr2 < 32; rr2 += 8)
    out[(size_t)(bx*32+rr2)*R + by*32 + tx] = f2b(tile[tx][rr2]);
}

// ---------------- bf16 MFMA GEMM (MLP) -----------------------------------------
template<int GELU, int OUTBF16>
__global__ __launch_bounds__(256) void mfma_gemm_kernel(
    const unsigned short* __restrict__ A, int lda,
    const unsigned short* __restrict__ BT, int ldbt,
    const float* __restrict__ bias,
    void* __restrict__ Cp, int ldc, int K, int mtiles) {
  __shared__ unsigned short As[128*32];
  __shared__ unsigned short Bs[128*32];
  int bm = blockIdx.x % mtiles;
  int bn = blockIdx.x / mtiles;
  int t = threadIdx.x;
  int lane = t & 63;
  int wid = t >> 6;
  int wm = wid >> 1, wn = wid & 1;

  f32x4 acc[4][4];
#pragma unroll
  for (int m = 0; m < 4; ++m)
#pragma unroll
    for (int n = 0; n < 4; ++n) acc[m][n] = (f32x4){0.f,0.f,0.f,0.f};

  const unsigned short* Abase = A + (size_t)bm*128*lda;
  const unsigned short* Bbase = BT + (size_t)bn*128*ldbt;
  int rr = lane & 15;
  int kg = (lane >> 4) * 8;

  for (int k0 = 0; k0 < K; k0 += 32) {
#pragma unroll
    for (int r = 0; r < 2; ++r) {
      int i = r*4096 + t*16;
      int row = i >> 6;
      int kc = (i & 63) >> 1;
      gload16(Abase + (size_t)row*lda + k0 + kc, (char*)As + r*4096 + wid*1024);
      gload16(Bbase + (size_t)row*ldbt + k0 + kc, (char*)Bs + r*4096 + wid*1024);
    }
    __syncthreads();
    bf16x8 af[4], bfr[4];
#pragma unroll
    for (int m = 0; m < 4; ++m)
      af[m] = *(const bf16x8*)&As[(wm*64 + m*16 + rr)*32 + kg];
#pragma unroll
    for (int n = 0; n < 4; ++n)
      bfr[n] = *(const bf16x8*)&Bs[(wn*64 + n*16 + rr)*32 + kg];
#pragma unroll
    for (int m = 0; m < 4; ++m)
#pragma unroll
      for (int n = 0; n < 4; ++n)
        acc[m][n] = __builtin_amdgcn_mfma_f32_16x16x32_bf16(af[m], bfr[n], acc[m][n], 0, 0, 0);
    __syncthreads();
  }

  int rq = lane >> 4;
#pragma unroll
  for (int m = 0; m < 4; ++m) {
#pragma unroll
    for (int n = 0; n < 4; ++n) {
      int grow0 = bm*128 + wm*64 + m*16 + rq*4;
      int gcol  = bn*128 + wn*64 + n*16 + rr;
#pragma unroll
      for (int j = 0; j < 4; ++j) {
        float v = acc[m][n][j];
        if (GELU) { v += bias[gcol]; v = 0.5f*v*(1.f + erff(v*0.70710678118654752f)); }
        if (OUTBF16)
          ((unsigned short*)Cp)[(size_t)(grow0+j)*ldc + gcol] = f2b(v);
        else
          ((float*)Cp)[(size_t)(grow0+j)*ldc + gcol] += v;
      }
    }
  }
}

extern "C" void kernel_launch(void* const* d_in, const int* in_sizes, int n_in,
                              void* d_out, int out_size, void* d_ws, size_t ws_size,
                              hipStream_t stream) {
  const float* x   = (const float*)d_in[0];
  const float* w1  = (const float*)d_in[1];
  const float* b1  = (const float*)d_in[2];
  const float* n1w = (const float*)d_in[3];
  const float* n1b = (const float*)d_in[4];
  const float* n2w = (const float*)d_in[5];
  const float* n2b = (const float*)d_in[6];
  const float* mw1 = (const float*)d_in[7];
  const float* mb1 = (const float*)d_in[8];
  const float* mw2 = (const float*)d_in[9];
  const float* mb2 = (const float*)d_in[10];
  float* out = (float*)d_out;

  char* ws = (char*)d_ws;
  const size_t MB = 1ull << 20;
  unsigned short* xn_h = (unsigned short*)(ws + 0*MB);
  unsigned short* xn_l = (unsigned short*)(ws + 26*MB);
  unsigned short* S1_h = (unsigned short*)(ws + 52*MB);
  unsigned short* S1_l = (unsigned short*)(ws + 78*MB);
  unsigned short* S2_h = (unsigned short*)(ws + 104*MB);
  unsigned short* S2_l = (unsigned short*)(ws + 130*MB);
  unsigned short* o1_h = (unsigned short*)(ws + 156*MB);
  unsigned short* o1_l = (unsigned short*)(ws + 182*MB);
  unsigned short* S3_h = (unsigned short*)(ws + 208*MB);
  unsigned short* S3_l = (unsigned short*)(ws + 234*MB);
  float*          xs   = (float*)(ws + 260*MB);
  unsigned short* xmb  = (unsigned short*)(ws + 312*MB);
  unsigned short* hid  = (unsigned short*)(ws + 338*MB);
  unsigned short* w1t  = (unsigned short*)(ws + 440*MB);
  unsigned short* w2t  = (unsigned short*)(ws + 442*MB);
  unsigned short* atab = (unsigned short*)(ws + 444*MB);

  init_tw<<<64, 256, 0, stream>>>(atab);
  convtr_kernel<<<(384/32)*(1536/32), 256, 0, stream>>>(mw1, w1t, 384, 1536);
  convtr_kernel<<<(1536/32)*(384/32), 256, 0, stream>>>(mw2, w2t, 1536, 384);

  // LN1 + transpose: x -> xn[b,h,c,w] hi/lo
  ln1t_kernel<<<512, 256, 0, stream>>>(x, n1w, n1b, xn_h, xn_l);
  // W-fwd: xn -> S1[b,h,m66,c]
  dft_kernel<0><<<512*3, 256, 0, stream>>>(atab, xn_h, xn_l, S1_h, S1_l,
                                           nullptr, nullptr, nullptr, nullptr);
  // H-fwd: S1 -> S2[b,comp,kh,kw,c]
  dft_kernel<1><<<264*3, 256, 0, stream>>>(atab, S1_h, S1_l, S2_h, S2_l,
                                           nullptr, nullptr, nullptr, nullptr);
  // block-diag complex matmul + ReLU: S2 -> o1[b,comp,kw,kh,c]
  blockmm2_kernel<<<HH*WF*NBK, 384, 0, stream>>>(S2_h, S2_l, w1, b1, o1_h, o1_l);
  // H-inv: o1 -> S3[b,kpack,h,c]
  dft_kernel<2><<<264*3, 256, 0, stream>>>(atab, o1_h, o1_l, S3_h, S3_l,
                                           nullptr, nullptr, nullptr, nullptr);
  // W-inv: S3 -> xs (fp32) and out = xs + x + b2
  dft_kernel<3><<<512*3, 256, 0, stream>>>(atab, S3_h, S3_l, nullptr, nullptr,
                                           x, mb2, xs, out);
  // LN2: xs -> xmb (bf16)
  ln_kernel<1><<<NTOK/4, 256, 0, stream>>>(xs, n2w, n2b, xmb);
  // GEMM1: hid = gelu(xm @ W1 + b1)  M=32768 N=1536 K=384
  mfma_gemm_kernel<1,1><<<256*12, 256, 0, stream>>>(xmb, 384, w1t, 384, mb1,
                                                    hid, 1536, 384, 256);
  // GEMM2: out += hid @ W2  M=32768 N=384 K=1536
  mfma_gemm_kernel<0,0><<<256*3, 256, 0, stream>>>(hid, 1536, w2t, 1536, nullptr,
                                                   out, 384, 1536, 256);
}

// Round 4
// 566.116 us; speedup vs baseline: 3.2487x; 1.1709x over previous
//
#include <hip/hip_runtime.h>
#include <math.h>

// AFNO block, MI355X. DFT stages as bf16 MFMA GEMMs vs constant twiddle tables
// (fp32 intermediates, data split hi/lo at staging, twiddle bf16-hi only);
// MLP as bf16 MFMA GEMMs; LN1 fused with transpose; residual fused into W-inv.

#define BB 8
#define CC 384
#define WF 33
#define NBK 8
#define BSZ 48
#define NTOK 32768
#define TW64 0.09817477042468103f  // 2*pi/64

// twiddle table element offsets (bf16)
#define T_AWF 0
#define T_AHF 5120
#define T_AHI 21504
#define T_AWI 37888

typedef __attribute__((ext_vector_type(8))) short bf16x8;
typedef __attribute__((ext_vector_type(4))) float f32x4;

__device__ __forceinline__ unsigned short f2b(float f) {
  union { float f; unsigned u; } x; x.f = f;
  unsigned u = x.u;
  return (unsigned short)((u + 0x7fffu + ((u >> 16) & 1u)) >> 16);
}
__device__ __forceinline__ float b2fl(unsigned short u) {
  return __uint_as_float(((unsigned)u) << 16);
}
__device__ __forceinline__ void gload16(const void* g, void* l) {
  __builtin_amdgcn_global_load_lds(
      (const __attribute__((address_space(1))) void*)g,
      (__attribute__((address_space(3))) void*)l, 16, 0, 0);
}

// ---------------- twiddle tables (bf16 hi only) --------------------------------
__global__ __launch_bounds__(256) void init_tw(unsigned short* __restrict__ A) {
  int idx0 = blockIdx.x * 256 + threadIdx.x;
  const float S = 0.125f;
  // AWf [80 m][64 w]: m=2kw+comp; comp0: cos/8, comp1: -sin/8 (0 for kw 0,32)
  for (int e = idx0; e < 5120; e += 16384) {
    int m = e >> 6, w = e & 63;
    float val = 0.f;
    if (m < 66) {
      int kwv = m >> 1;
      float th = (float)((kwv * w) & 63) * TW64;
      val = (m & 1) ? (((kwv==0)||(kwv==32)) ? 0.f : -sinf(th)*S) : cosf(th)*S;
    }
    A[T_AWF + e] = f2b(val);
  }
  // AHf/AHi [comp_in 2][m'=(comp_out,k) 128][n 64]
  for (int e = idx0; e < 16384; e += 16384) {
    int comp = e >> 13; int r = e & 8191; int mp = r >> 6, hh = r & 63;
    int cpo = mp >> 6, kh = mp & 63;
    float th = (float)((kh * hh) & 63) * TW64;
    float cv = cosf(th), sv = sinf(th);
    float fv = (cpo == 0) ? (comp == 0 ? cv : sv) : (comp == 0 ? -sv : cv);
    A[T_AHF + e] = f2b(fv * S);
    float iv = (cpo == 0) ? (comp == 0 ? cv : -sv) : (comp == 0 ? sv : cv);
    A[T_AHI + e] = f2b(iv * S);
  }
  // AWi [w 64][kpack 64]
  for (int e = idx0; e < 4096; e += 16384) {
    int w = e >> 6, kp = e & 63;
    float val;
    if (kp <= 32) {
      float th = (float)((kp * w) & 63) * TW64;
      val = cosf(th) * (((kp==0)||(kp==32)) ? 1.f : 2.f) * S;
    } else {
      int k2 = kp - 32;
      float th = (float)((k2 * w) & 63) * TW64;
      val = -2.f * sinf(th) * S;
    }
    A[T_AWI + e] = f2b(val);
  }
}

// ---------------- LN1 fused with transpose: x[b,h,w,c] -> xn[b,h,c,w] fp32 -----
__global__ __launch_bounds__(256) void ln1t_kernel(const float* __restrict__ x,
    const float* __restrict__ g, const float* __restrict__ be, float* __restrict__ xn) {
  int outer = blockIdx.x;  // b*64+h
  int tid = threadIdx.x, lane = tid & 63, wg = tid >> 6;
  const float* base = x + (size_t)outer * 64 * 384;
  float s[16], s2[16];
#pragma unroll
  for (int q = 0; q < 16; ++q) { s[q] = 0.f; s2[q] = 0.f; }
  for (int ch = 0; ch < 6; ++ch) {
#pragma unroll
    for (int q = 0; q < 16; ++q) {
      float v = base[(size_t)(wg*16 + q)*384 + ch*64 + lane];
      s[q] += v; s2[q] += v*v;
    }
  }
#pragma unroll
  for (int q = 0; q < 16; ++q) {
#pragma unroll
    for (int off = 32; off >= 1; off >>= 1) {
      s[q] += __shfl_xor(s[q], off);
      s2[q] += __shfl_xor(s2[q], off);
    }
  }
  float mu[16], rs[16];
#pragma unroll
  for (int q = 0; q < 16; ++q) {
    mu[q] = s[q] * (1.f/384.f);
    rs[q] = rsqrtf(s2[q] * (1.f/384.f) - mu[q]*mu[q] + 1e-5f);
  }
  float* o = xn + (size_t)outer * 384 * 64;
  for (int ch = 0; ch < 6; ++ch) {
    int c = ch*64 + lane;
    float ga = g[c], bb2 = be[c];
#pragma unroll
    for (int qq = 0; qq < 4; ++qq) {
      float4 ov;
      float t0, t1, t2, t3;
      { int q = qq*4+0; t0 = (base[(size_t)(wg*16+q)*384 + c]-mu[q])*rs[q]*ga + bb2; }
      { int q = qq*4+1; t1 = (base[(size_t)(wg*16+q)*384 + c]-mu[q])*rs[q]*ga + bb2; }
      { int q = qq*4+2; t2 = (base[(size_t)(wg*16+q)*384 + c]-mu[q])*rs[q]*ga + bb2; }
      { int q = qq*4+3; t3 = (base[(size_t)(wg*16+q)*384 + c]-mu[q])*rs[q]*ga + bb2; }
      ov.x = t0; ov.y = t1; ov.z = t2; ov.w = t3;
      *(float4*)(o + (size_t)c*64 + wg*16 + qq*4) = ov;
    }
  }
}

// ---------------- DFT stage as MFMA GEMM ---------------------------------------
// STAGE: 0=W-fwd, 1=H-fwd, 2=H-inv, 3=W-inv(+residual,+xs bf16)
// C[M x 128c] = sum_comp A_comp[M x 64] * (Bh_comp + Bl_comp)[64 x 128c]
template<int STAGE>
__global__ __launch_bounds__(256) void dft_kernel(
    const unsigned short* __restrict__ A0, const float* __restrict__ D,
    float* __restrict__ O, const float* __restrict__ xres,
    const float* __restrict__ b2, unsigned short* __restrict__ xsb,
    float* __restrict__ outp) {
  constexpr int M = (STAGE==0) ? 80 : (STAGE==3) ? 64 : 128;
  constexpr int MT = M / 16;
  constexpr int NA = (STAGE==1 || STAGE==2) ? 2 : 1;
  constexpr int ABYTES = NA * M * 128;
  constexpr int STG = ABYTES + 32768;
  constexpr int EPB = M * 128 * 4;
  constexpr int SB = (STG > EPB) ? STG : EPB;
  __shared__ __align__(16) char smem[SB];
  char* BhB = smem + ABYTES;
  char* BlB = BhB + 16384;

  int bid = blockIdx.x;
  int cc = bid % 3; int outer = bid / 3;
  int c0 = cc * 128;
  int tid = threadIdx.x, lane = tid & 63, wid = tid >> 6;
  int rr = lane & 15, rq = lane >> 4;
  int b, h = 0, kw = 0;
  if (STAGE == 0 || STAGE == 3) { b = outer >> 6; h = outer & 63; }
  else { b = outer / 33; kw = outer % 33; }

  f32x4 acc[MT][2];
#pragma unroll
  for (int mt = 0; mt < MT; ++mt)
#pragma unroll
    for (int nt = 0; nt < 2; ++nt) acc[mt][nt] = (f32x4){0.f,0.f,0.f,0.f};

  // ---- stage A tables (all comps resident), 16B-XOR source pre-swizzle ----
  const unsigned short* Atab =
    (STAGE==0) ? A0+T_AWF : (STAGE==1) ? A0+T_AHF : (STAGE==2) ? A0+T_AHI : A0+T_AWI;
#pragma unroll
  for (int i = 0; i < NA*M*8; i += 256) {
    int t2 = tid + i;
    if (t2 < NA*M*8) {
      int mm = t2 >> 3, blk = t2 & 7;
      gload16(Atab + mm*64 + ((blk ^ (mm & 7)) << 3),
              smem + (i/256)*4096 + wid*1024);
    }
  }

  int ncomp = (STAGE == 1) ? ((kw == 0 || kw == 32) ? 1 : 2) : NA;

  for (int comp = 0; comp < ncomp; ++comp) {
    if (comp) __syncthreads();
    // ---- stage B tile [c 128][k 64] as hi/lo bf16 planes ----
    if (STAGE == 0) {
      const float* src = D + (size_t)(b*64 + h)*384*64 + (size_t)c0*64;
#pragma unroll
      for (int i = 0; i < 8; ++i) {
        int t2 = tid + i*256;
        int kq = t2 >> 7, c = t2 & 127;
        float4 v = *(const float4*)(src + (size_t)c*64 + kq*4);
        unsigned short h0 = f2b(v.x), h1 = f2b(v.y), h2 = f2b(v.z), h3 = f2b(v.w);
        unsigned short l0 = f2b(v.x - b2fl(h0)), l1 = f2b(v.y - b2fl(h1));
        unsigned short l2 = f2b(v.z - b2fl(h2)), l3 = f2b(v.w - b2fl(h3));
        int byteo = c*128 + ((kq*8) ^ ((c & 7) << 4));
        uint2 ph; ph.x = h0 | ((unsigned)h1 << 16); ph.y = h2 | ((unsigned)h3 << 16);
        uint2 pl; pl.x = l0 | ((unsigned)l1 << 16); pl.y = l2 | ((unsigned)l3 << 16);
        *(uint2*)(BhB + byteo) = ph;
        *(uint2*)(BlB + byteo) = pl;
      }
    } else {
      size_t P; int RS;
      if (STAGE == 1) { P = (size_t)b*(64*66*384) + (size_t)(2*kw + comp)*384 + c0; RS = 66*384; }
      else if (STAGE == 2) { P = ((size_t)((b*2 + comp)*33) + kw)*64*384 + c0; RS = 384; }
      else { P = (size_t)b*(64*64*384) + (size_t)h*384 + c0; RS = 64*384; }
      const float* p0 = D + P;
#pragma unroll
      for (int i = 0; i < 8; ++i) {
        int t2 = tid + i*256;
        int kq = t2 >> 7, c = t2 & 127;
        const float* p = p0 + (size_t)(4*kq)*RS + c;
        float v0 = p[0], v1 = p[RS], v2 = p[2*(size_t)RS], v3 = p[3*(size_t)RS];
        unsigned short h0 = f2b(v0), h1 = f2b(v1), h2 = f2b(v2), h3 = f2b(v3);
        unsigned short l0 = f2b(v0 - b2fl(h0)), l1 = f2b(v1 - b2fl(h1));
        unsigned short l2 = f2b(v2 - b2fl(h2)), l3 = f2b(v3 - b2fl(h3));
        int byteo = c*128 + ((kq*8) ^ ((c & 7) << 4));
        uint2 ph; ph.x = h0 | ((unsigned)h1 << 16); ph.y = h2 | ((unsigned)h3 << 16);
        uint2 pl; pl.x = l0 | ((unsigned)l1 << 16); pl.y = l2 | ((unsigned)l3 << 16);
        *(uint2*)(BhB + byteo) = ph;
        *(uint2*)(BlB + byteo) = pl;
      }
    }
    __syncthreads();
    // ---- MFMA: acc += A[comp]*(Bh + Bl) ----
#pragma unroll
    for (int kh2 = 0; kh2 < 2; ++kh2) {
      int kb = kh2*64 + rq*16;
      bf16x8 bh[2], bl[2];
#pragma unroll
      for (int nt = 0; nt < 2; ++nt) {
        int n = wid*32 + nt*16 + rr;
        int off = n*128 + (kb ^ ((n & 7) << 4));
        bh[nt] = *(const bf16x8*)(BhB + off);
        bl[nt] = *(const bf16x8*)(BlB + off);
      }
#pragma unroll
      for (int mt = 0; mt < MT; ++mt) {
        int mr = mt*16 + rr;
        bf16x8 af = *(const bf16x8*)(smem + comp*M*128 + mr*128 + (kb ^ ((mr & 7) << 4)));
#pragma unroll
        for (int nt = 0; nt < 2; ++nt) {
          acc[mt][nt] = __builtin_amdgcn_mfma_f32_16x16x32_bf16(af, bh[nt], acc[mt][nt], 0, 0, 0);
          acc[mt][nt] = __builtin_amdgcn_mfma_f32_16x16x32_bf16(af, bl[nt], acc[mt][nt], 0, 0, 0);
        }
      }
    }
  }
  __syncthreads();

  // ---- epilogue: repack to LDS fp32 [M][128] (XOR-swz), coalesced stores ----
  float* ep = (float*)smem;
#pragma unroll
  for (int mt = 0; mt < MT; ++mt)
#pragma unroll
    for (int nt = 0; nt < 2; ++nt)
#pragma unroll
      for (int j = 0; j < 4; ++j) {
        int m = mt*16 + rq*4 + j;
        int cl = wid*32 + nt*16 + rr;
        ep[m*128 + (cl ^ ((m & 7) << 2))] = acc[mt][nt][j];
      }
  __syncthreads();

  if (STAGE < 3) {
    for (int it = tid; it < M*32; it += 256) {
      int m = it >> 5, u = it & 31;
      if (STAGE == 0 && m >= 66) continue;
      if (STAGE == 2) { int cp = m >> 6; if (cp && (kw == 0 || kw == 32)) continue; }
      float4 v = *(const float4*)(ep + m*128 + ((u*4) ^ ((m & 7) << 2)));
      size_t rowb;
      if (STAGE == 0) rowb = ((size_t)(b*64 + h)*66 + m)*384 + c0;
      else if (STAGE == 1) { int cp = m >> 6, kh = m & 63;
        rowb = (((size_t)((b*2 + cp)*64 + kh)*33) + kw)*384 + c0; }
      else { int cp = m >> 6, h2 = m & 63; int kp = cp ? 32 + kw : kw;
        rowb = ((size_t)(b*64 + kp)*64 + h2)*384 + c0; }
      *(float4*)(O + rowb + u*4) = v;
    }
  } else {
    for (int it = tid; it < 64*32; it += 256) {
      int m = it >> 5, u = it & 31;
      float4 v = *(const float4*)(ep + m*128 + ((u*4) ^ ((m & 7) << 2)));
      size_t idx = ((size_t)(b*64 + h)*64 + m)*384 + c0 + u*4;
      float4 rx = *(const float4*)(xres + idx);
      float4 ov;
      ov.x = v.x + rx.x + b2[c0 + u*4 + 0];
      ov.y = v.y + rx.y + b2[c0 + u*4 + 1];
      ov.z = v.z + rx.z + b2[c0 + u*4 + 2];
      ov.w = v.w + rx.w + b2[c0 + u*4 + 3];
      *(float4*)(outp + idx) = ov;
    }
    for (int it = tid; it < 64*16; it += 256) {
      int m = it >> 4, u8 = it & 15;
      unsigned short hv[8];
#pragma unroll
      for (int k2 = 0; k2 < 8; ++k2) {
        int cl = u8*8 + k2;
        hv[k2] = f2b(ep[m*128 + (cl ^ ((m & 7) << 2))]);
      }
      uint4 pw;
      pw.x = hv[0] | ((unsigned)hv[1] << 16);
      pw.y = hv[2] | ((unsigned)hv[3] << 16);
      pw.z = hv[4] | ((unsigned)hv[5] << 16);
      pw.w = hv[6] | ((unsigned)hv[7] << 16);
      *(uint4*)(xsb + ((size_t)(b*64 + h)*64 + m)*384 + c0 + u8*8) = pw;
    }
  }
}

// ---------------- per-mode block-diag complex matmul + bias + split ReLU -------
__global__ __launch_bounds__(384) void blockmm2_kernel(
    const float* __restrict__ S2, const float* __restrict__ w1,
    const float* __restrict__ b1, float* __restrict__ o1) {
  int bid = blockIdx.x;
  int n = bid % NBK;
  int kw = (bid / NBK) % WF;
  int h = bid / (NBK*WF);
  int tid = threadIdx.x;
  __shared__ float2 wl[BSZ*BSZ];
  __shared__ float2 xl2[BB][BSZ];
  __shared__ float2 bl[BSZ];
  const float2* wbase = (const float2*)w1 + ((size_t)(h*WF + kw)*NBK + n)*(BSZ*BSZ);
  for (int t = tid; t < BSZ*BSZ; t += 384) wl[t] = wbase[t];
  const float2* bbase = (const float2*)b1 + ((size_t)(h*WF + kw)*NBK + n)*BSZ;
  if (tid < BSZ) bl[tid] = bbase[tid];
  {
    int bb = tid / BSZ, i = tid % BSZ;
    size_t ir = (((size_t)((bb*2 + 0)*64 + h)*33) + kw)*384 + n*48 + i;
    size_t ii = (((size_t)((bb*2 + 1)*64 + h)*33) + kw)*384 + n*48 + i;
    xl2[bb][i] = make_float2(S2[ir], S2[ii]);
  }
  __syncthreads();
  int bb = tid / BSZ, o = tid % BSZ;
  float2 acc = bl[o];
#pragma unroll
  for (int i = 0; i < BSZ; ++i) {
    float2 xv = xl2[bb][i];
    float2 wv = wl[i*BSZ + o];
    acc.x += xv.x*wv.x - xv.y*wv.y;
    acc.y += xv.x*wv.y + xv.y*wv.x;
  }
  size_t idr = (((size_t)((bb*2 + 0)*33) + kw)*64 + h)*384 + n*48 + o;
  size_t idi = (((size_t)((bb*2 + 1)*33) + kw)*64 + h)*384 + n*48 + o;
  o1[idr] = fmaxf(acc.x, 0.f);
  o1[idi] = fmaxf(acc.y, 0.f);
}

// ---------------- LN2: bf16 in -> bf16 out -------------------------------------
__global__ __launch_bounds__(256) void ln2_kernel(const unsigned short* __restrict__ in,
    const float* __restrict__ g, const float* __restrict__ bsh,
    unsigned short* __restrict__ outp) {
  int token = blockIdx.x * 4 + (threadIdx.x >> 6);
  int lane = threadIdx.x & 63;
  const unsigned short* row = in + (size_t)token * CC;
  float v[6]; float s = 0.f;
#pragma unroll
  for (int j = 0; j < 6; ++j) { v[j] = b2fl(row[lane + 64*j]); s += v[j]; }
#pragma unroll
  for (int off = 32; off >= 1; off >>= 1) s += __shfl_xor(s, off);
  float mu = s * (1.0f/CC);
  float q = 0.f;
#pragma unroll
  for (int j = 0; j < 6; ++j) { float d = v[j] - mu; q += d*d; }
#pragma unroll
  for (int off = 32; off >= 1; off >>= 1) q += __shfl_xor(q, off);
  float rs = rsqrtf(q * (1.0f/CC) + 1e-5f);
#pragma unroll
  for (int j = 0; j < 6; ++j) {
    int c = lane + 64*j;
    outp[(size_t)token*CC + c] = f2b((v[j]-mu)*rs*g[c] + bsh[c]);
  }
}

// ---------------- transpose + fp32->bf16 convert (weights) ---------------------
__global__ __launch_bounds__(256) void convtr_kernel(const float* __restrict__ in,
    unsigned short* __restrict__ out, int R, int C) {
  __shared__ float tile[32][33];
  int ntc = C >> 5;
  int bx = blockIdx.x % ntc;
  int by = blockIdx.x / ntc;
  int tx = threadIdx.x & 31, ty = threadIdx.x >> 5;
  for (int rr2 = ty; rr2 < 32; rr2 += 8)
    tile[rr2][tx] = in[(size_t)(by*32+rr2)*C + bx*32 + tx];
  __syncthreads();
  for (int rr2 = ty; rr2 < 32; rr2 += 8)
    out[(size_t)(bx*32+rr2)*R + by*32 + tx] = f2b(tile[tx][rr2]);
}

// ---------------- bf16 MFMA GEMM (MLP) -----------------------------------------
template<int GELU, int OUTBF16>
__global__ __launch_bounds__(256) void mfma_gemm_kernel(
    const unsigned short* __restrict__ A, int lda,
    const unsigned short* __restrict__ BT, int ldbt,
    const float* __restrict__ bias,
    void* __restrict__ Cp, int ldc, int K, int mtiles) {
  __shared__ unsigned short As[128*32];
  __shared__ unsigned short Bs[128*32];
  int bm = blockIdx.x % mtiles;
  int bn = blockIdx.x / mtiles;
  int t = threadIdx.x;
  int lane = t & 63;
  int wid = t >> 6;
  int wm = wid >> 1, wn = wid & 1;

  f32x4 acc[4][4];
#pragma unroll
  for (int m = 0; m < 4; ++m)
#pragma unroll
    for (int n = 0; n < 4; ++n) acc[m][n] = (f32x4){0.f,0.f,0.f,0.f};

  const unsigned short* Abase = A + (size_t)bm*128*lda;
  const unsigned short* Bbase = BT + (size_t)bn*128*ldbt;
  int rr = lane & 15;
  int kg = (lane >> 4) * 8;

  for (int k0 = 0; k0 < K; k0 += 32) {
#pragma unroll
    for (int r = 0; r < 2; ++r) {
      int i = r*4096 + t*16;
      int row = i >> 6;
      int kc = (i & 63) >> 1;
      gload16(Abase + (size_t)row*lda + k0 + kc, (char*)As + r*4096 + wid*1024);
      gload16(Bbase + (size_t)row*ldbt + k0 + kc, (char*)Bs + r*4096 + wid*1024);
    }
    __syncthreads();
    bf16x8 af[4], bfr[4];
#pragma unroll
    for (int m = 0; m < 4; ++m)
      af[m] = *(const bf16x8*)&As[(wm*64 + m*16 + rr)*32 + kg];
#pragma unroll
    for (int n = 0; n < 4; ++n)
      bfr[n] = *(const bf16x8*)&Bs[(wn*64 + n*16 + rr)*32 + kg];
#pragma unroll
    for (int m = 0; m < 4; ++m)
#pragma unroll
      for (int n = 0; n < 4; ++n)
        acc[m][n] = __builtin_amdgcn_mfma_f32_16x16x32_bf16(af[m], bfr[n], acc[m][n], 0, 0, 0);
    __syncthreads();
  }

  int rq = lane >> 4;
#pragma unroll
  for (int m = 0; m < 4; ++m) {
#pragma unroll
    for (int n = 0; n < 4; ++n) {
      int grow0 = bm*128 + wm*64 + m*16 + rq*4;
      int gcol  = bn*128 + wn*64 + n*16 + rr;
#pragma unroll
      for (int j = 0; j < 4; ++j) {
        float v = acc[m][n][j];
        if (GELU) { v += bias[gcol]; v = 0.5f*v*(1.f + erff(v*0.70710678118654752f)); }
        if (OUTBF16)
          ((unsigned short*)Cp)[(size_t)(grow0+j)*ldc + gcol] = f2b(v);
        else
          ((float*)Cp)[(size_t)(grow0+j)*ldc + gcol] += v;
      }
    }
  }
}

extern "C" void kernel_launch(void* const* d_in, const int* in_sizes, int n_in,
                              void* d_out, int out_size, void* d_ws, size_t ws_size,
                              hipStream_t stream) {
  const float* x   = (const float*)d_in[0];
  const float* w1  = (const float*)d_in[1];
  const float* b1  = (const float*)d_in[2];
  const float* n1w = (const float*)d_in[3];
  const float* n1b = (const float*)d_in[4];
  const float* n2w = (const float*)d_in[5];
  const float* n2b = (const float*)d_in[6];
  const float* mw1 = (const float*)d_in[7];
  const float* mb1 = (const float*)d_in[8];
  const float* mw2 = (const float*)d_in[9];
  const float* mb2 = (const float*)d_in[10];
  float* out = (float*)d_out;

  char* ws = (char*)d_ws;
  const size_t MB = 1ull << 20;
  float* xn  = (float*)ws;                              // 50.3 MB [b,h,c,w]
  float* S1  = (float*)(ws + 52*MB);                    // 51.9 [b,h,m66,c]
  float* S2  = (float*)(ws + 105*MB);                   // 51.9 [b2cp,kh,kw,c]
  float* o1  = (float*)(ws + 158*MB);                   // 51.9 [b2cp,kw,kh,c]
  float* S3  = (float*)(ws + 211*MB);                   // 50.3 [b,kp,h,c]
  unsigned short* xsb = (unsigned short*)(ws + 262*MB); // 25.2 bf16 xs
  unsigned short* xmb = (unsigned short*)(ws + 288*MB); // 25.2 bf16 LN2 out
  unsigned short* hid = (unsigned short*)(ws + 314*MB); // 100.7 bf16
  unsigned short* w1t = (unsigned short*)(ws + 415*MB);
  unsigned short* w2t = (unsigned short*)(ws + 417*MB);
  unsigned short* atab = (unsigned short*)(ws + 419*MB);

  init_tw<<<64, 256, 0, stream>>>(atab);
  convtr_kernel<<<(384/32)*(1536/32), 256, 0, stream>>>(mw1, w1t, 384, 1536);
  convtr_kernel<<<(1536/32)*(384/32), 256, 0, stream>>>(mw2, w2t, 1536, 384);

  // LN1 + transpose
  ln1t_kernel<<<512, 256, 0, stream>>>(x, n1w, n1b, xn);
  // W-fwd
  dft_kernel<0><<<512*3, 256, 0, stream>>>(atab, xn, S1, nullptr, nullptr, nullptr, nullptr);
  // H-fwd
  dft_kernel<1><<<264*3, 256, 0, stream>>>(atab, S1, S2, nullptr, nullptr, nullptr, nullptr);
  // block-diag complex matmul + ReLU
  blockmm2_kernel<<<64*WF*NBK, 384, 0, stream>>>(S2, w1, b1, o1);
  // H-inv
  dft_kernel<2><<<264*3, 256, 0, stream>>>(atab, o1, S3, nullptr, nullptr, nullptr, nullptr);
  // W-inv + residual + xs(bf16)
  dft_kernel<3><<<512*3, 256, 0, stream>>>(atab, S3, nullptr, x, mb2, xsb, out);
  // LN2
  ln2_kernel<<<NTOK/4, 256, 0, stream>>>(xsb, n2w, n2b, xmb);
  // GEMM1: hid = gelu(xm @ W1 + b1)  M=32768 N=1536 K=384
  mfma_gemm_kernel<1,1><<<256*12, 256, 0, stream>>>(xmb, 384, w1t, 384, mb1,
                                                    hid, 1536, 384, 256);
  // GEMM2: out += hid @ W2  M=32768 N=384 K=1536
  mfma_gemm_kernel<0,0><<<256*3, 256, 0, stream>>>(hid, 1536, w2t, 1536, nullptr,
                                                   out, 384, 1536, 256);
}

// Round 5
// 406.685 us; speedup vs baseline: 4.5223x; 1.3920x over previous
//
#include <hip/hip_runtime.h>
#include <math.h>

// AFNO block, MI355X. Spectral path: bf16 MFMA DFT stages vs constant twiddle
// tables, single-bf16 intermediates. MLP: bf16 MFMA GEMMs, BK=64, XOR-swizzled
// LDS (conflict-free ds_read_b128). LN1 fused w/ transpose; residual in W-inv.

#define BB 8
#define CC 384
#define WF 33
#define NBK 8
#define BSZ 48
#define NTOK 32768
#define TW64 0.09817477042468103f  // 2*pi/64

// twiddle table element offsets (bf16)
#define T_AWF 0
#define T_AHF 5120
#define T_AHI 21504
#define T_AWI 37888

typedef __attribute__((ext_vector_type(8))) short bf16x8;
typedef __attribute__((ext_vector_type(4))) float f32x4;

__device__ __forceinline__ unsigned short f2b(float f) {
  union { float f; unsigned u; } x; x.f = f;
  unsigned u = x.u;
  return (unsigned short)((u + 0x7fffu + ((u >> 16) & 1u)) >> 16);
}
__device__ __forceinline__ float b2fl(unsigned short u) {
  return __uint_as_float(((unsigned)u) << 16);
}
__device__ __forceinline__ void gload16(const void* g, void* l) {
  __builtin_amdgcn_global_load_lds(
      (const __attribute__((address_space(1))) void*)g,
      (__attribute__((address_space(3))) void*)l, 16, 0, 0);
}

// ---------------- twiddle tables (bf16) ----------------------------------------
__global__ __launch_bounds__(256) void init_tw(unsigned short* __restrict__ A) {
  int idx0 = blockIdx.x * 256 + threadIdx.x;
  const float S = 0.125f;
  // AWf [80 m][64 w]: m=2kw+comp; comp0: cos/8, comp1: -sin/8 (0 for kw 0,32)
  for (int e = idx0; e < 5120; e += 16384) {
    int m = e >> 6, w = e & 63;
    float val = 0.f;
    if (m < 66) {
      int kwv = m >> 1;
      float th = (float)((kwv * w) & 63) * TW64;
      val = (m & 1) ? (((kwv==0)||(kwv==32)) ? 0.f : -sinf(th)*S) : cosf(th)*S;
    }
    A[T_AWF + e] = f2b(val);
  }
  // AHf/AHi [comp_in 2][m'=(comp_out,k) 128][n 64]
  for (int e = idx0; e < 16384; e += 16384) {
    int comp = e >> 13; int r = e & 8191; int mp = r >> 6, hh = r & 63;
    int cpo = mp >> 6, kh = mp & 63;
    float th = (float)((kh * hh) & 63) * TW64;
    float cv = cosf(th), sv = sinf(th);
    float fv = (cpo == 0) ? (comp == 0 ? cv : sv) : (comp == 0 ? -sv : cv);
    A[T_AHF + e] = f2b(fv * S);
    float iv = (cpo == 0) ? (comp == 0 ? cv : -sv) : (comp == 0 ? sv : cv);
    A[T_AHI + e] = f2b(iv * S);
  }
  // AWi [w 64][kpack 64]
  for (int e = idx0; e < 4096; e += 16384) {
    int w = e >> 6, kp = e & 63;
    float val;
    if (kp <= 32) {
      float th = (float)((kp * w) & 63) * TW64;
      val = cosf(th) * (((kp==0)||(kp==32)) ? 1.f : 2.f) * S;
    } else {
      int k2 = kp - 32;
      float th = (float)((k2 * w) & 63) * TW64;
      val = -2.f * sinf(th) * S;
    }
    A[T_AWI + e] = f2b(val);
  }
}

// ---------------- LN1 fused with transpose: x[b,h,w,c] -> xn[b,h,c,w] bf16 -----
__global__ __launch_bounds__(256) void ln1t_kernel(const float* __restrict__ x,
    const float* __restrict__ g, const float* __restrict__ be,
    unsigned short* __restrict__ xn) {
  int outer = blockIdx.x;  // b*64+h
  int tid = threadIdx.x, lane = tid & 63, wg = tid >> 6;
  const float* base = x + (size_t)outer * 64 * 384;
  float s[16], s2[16];
#pragma unroll
  for (int q = 0; q < 16; ++q) { s[q] = 0.f; s2[q] = 0.f; }
  for (int ch = 0; ch < 6; ++ch) {
#pragma unroll
    for (int q = 0; q < 16; ++q) {
      float v = base[(size_t)(wg*16 + q)*384 + ch*64 + lane];
      s[q] += v; s2[q] += v*v;
    }
  }
#pragma unroll
  for (int q = 0; q < 16; ++q) {
#pragma unroll
    for (int off = 32; off >= 1; off >>= 1) {
      s[q] += __shfl_xor(s[q], off);
      s2[q] += __shfl_xor(s2[q], off);
    }
  }
  float mu[16], rs[16];
#pragma unroll
  for (int q = 0; q < 16; ++q) {
    mu[q] = s[q] * (1.f/384.f);
    rs[q] = rsqrtf(s2[q] * (1.f/384.f) - mu[q]*mu[q] + 1e-5f);
  }
  unsigned short* o = xn + (size_t)outer * 384 * 64;
  for (int ch = 0; ch < 6; ++ch) {
    int c = ch*64 + lane;
    float ga = g[c], bb2 = be[c];
#pragma unroll
    for (int qq = 0; qq < 4; ++qq) {
      unsigned short hv[4];
#pragma unroll
      for (int r2 = 0; r2 < 4; ++r2) {
        int q = qq*4 + r2;
        hv[r2] = f2b((base[(size_t)(wg*16+q)*384 + c]-mu[q])*rs[q]*ga + bb2);
      }
      uint2 pw;
      pw.x = hv[0] | ((unsigned)hv[1] << 16);
      pw.y = hv[2] | ((unsigned)hv[3] << 16);
      *(uint2*)(o + (size_t)c*64 + wg*16 + qq*4) = pw;
    }
  }
}

// ---------------- DFT stage as MFMA GEMM (single bf16 plane) -------------------
// STAGE: 0=W-fwd, 1=H-fwd, 2=H-inv, 3=W-inv(+residual,+xs bf16)
template<int STAGE>
__global__ __launch_bounds__(256) void dft_kernel(
    const unsigned short* __restrict__ A0, const unsigned short* __restrict__ D,
    unsigned short* __restrict__ O, const float* __restrict__ xres,
    const float* __restrict__ b2, unsigned short* __restrict__ xsb,
    float* __restrict__ outp) {
  constexpr int M = (STAGE==0) ? 80 : (STAGE==3) ? 64 : 128;
  constexpr int MT = M / 16;
  constexpr int NA = (STAGE==1 || STAGE==2) ? 2 : 1;
  constexpr int ABYTES = NA * M * 128;
  constexpr int STG = ABYTES + 16384;
  constexpr int EPB = 64 * 128 * 4;       // 32 KB half-epilogue
  constexpr int SB = (STG > EPB) ? STG : EPB;
  __shared__ __align__(16) char smem[SB];
  char* BPL = smem + ABYTES;              // B plane, 16 KB

  int bid = blockIdx.x;
  int cc = bid % 3; int outer = bid / 3;
  int c0 = cc * 128;
  int tid = threadIdx.x, lane = tid & 63, wid = tid >> 6;
  int rr = lane & 15, rq = lane >> 4;
  int b, h = 0, kw = 0;
  if (STAGE == 0 || STAGE == 3) { b = outer >> 6; h = outer & 63; }
  else { b = outer / 33; kw = outer % 33; }

  f32x4 acc[MT][2];
#pragma unroll
  for (int mt = 0; mt < MT; ++mt)
#pragma unroll
    for (int nt = 0; nt < 2; ++nt) acc[mt][nt] = (f32x4){0.f,0.f,0.f,0.f};

  // ---- stage A tables (all comps), 16B-chunk XOR source pre-swizzle ----
  const unsigned short* Atab =
    (STAGE==0) ? A0+T_AWF : (STAGE==1) ? A0+T_AHF : (STAGE==2) ? A0+T_AHI : A0+T_AWI;
  constexpr int ACH = NA * M * 8;  // 16B chunks
#pragma unroll
  for (int i = 0; i < (ACH + 255)/256; ++i) {
    int t2 = tid + i*256;
    if ((ACH % 256 == 0) || (t2 < ACH)) {
      int mm = t2 >> 3, ch = t2 & 7;
      gload16(Atab + mm*64 + ((ch ^ (mm & 7)) << 3), smem + i*4096 + wid*1024);
    }
  }

  int ncomp = (STAGE == 1) ? ((kw == 0 || kw == 32) ? 1 : 2) : NA;

  for (int comp = 0; comp < ncomp; ++comp) {
    if (comp) __syncthreads();
    // ---- stage B tile [c 128][k 64] bf16 ----
    if (STAGE == 0) {
      const unsigned short* src = D + (((size_t)(b*64 + h))*384 + c0) * 64;
#pragma unroll
      for (int i = 0; i < 4; ++i) {
        int idx = tid + i*256;
        int c = idx >> 3, ch = idx & 7;
        gload16(src + c*64 + ((ch ^ (c & 7)) << 3), BPL + i*4096 + wid*1024);
      }
    } else {
      size_t P; int RS;
      if (STAGE == 1) { P = (size_t)b*(64*66*384) + (size_t)(2*kw + comp)*384 + c0; RS = 66*384; }
      else if (STAGE == 2) { P = ((size_t)((b*2 + comp)*33) + kw)*64*384 + c0; RS = 384; }
      else { P = (size_t)b*(64*64*384) + (size_t)h*384 + c0; RS = 64*384; }
      const unsigned short* p0 = D + P;
#pragma unroll
      for (int i = 0; i < 4; ++i) {
        int kq = (tid >> 6) + i*4;         // 0..15, 4 k each
        int c2 = (tid & 63) * 2;
        const unsigned short* p = p0 + (size_t)(4*kq)*RS + c2;
        unsigned u0 = *(const unsigned*)p;
        unsigned u1 = *(const unsigned*)(p + RS);
        unsigned u2 = *(const unsigned*)(p + 2*(size_t)RS);
        unsigned u3 = *(const unsigned*)(p + 3*(size_t)RS);
        uint2 w0, w1v;
        w0.x = (u0 & 0xffffu) | (u1 << 16);
        w0.y = (u2 & 0xffffu) | (u3 << 16);
        w1v.x = (u0 >> 16) | (u1 & 0xffff0000u);
        w1v.y = (u2 >> 16) | (u3 & 0xffff0000u);
        *(uint2*)(BPL + c2*128 + ((kq*8) ^ ((c2 & 7) << 4))) = w0;
        *(uint2*)(BPL + (c2+1)*128 + ((kq*8) ^ (((c2+1) & 7) << 4))) = w1v;
      }
    }
    __syncthreads();
    // ---- MFMA ----
#pragma unroll
    for (int kh2 = 0; kh2 < 2; ++kh2) {
      int chb = kh2*4 + rq;                // 16B chunk index 0..7
      bf16x8 bfr[2];
#pragma unroll
      for (int nt = 0; nt < 2; ++nt) {
        int n = wid*32 + nt*16 + rr;
        bfr[nt] = *(const bf16x8*)(BPL + n*128 + ((chb ^ (n & 7)) << 4));
      }
#pragma unroll
      for (int mt = 0; mt < MT; ++mt) {
        int mr = mt*16 + rr;
        bf16x8 af = *(const bf16x8*)(smem + comp*(M*128) + mr*128 + ((chb ^ (mr & 7)) << 4));
#pragma unroll
        for (int nt = 0; nt < 2; ++nt)
          acc[mt][nt] = __builtin_amdgcn_mfma_f32_16x16x32_bf16(af, bfr[nt], acc[mt][nt], 0, 0, 0);
      }
    }
  }
  __syncthreads();

  // ---- epilogue in 64-row halves: repack fp32 -> LDS (XOR swz), coalesced out
  float* ep = (float*)smem;
  constexpr int NHM = (M + 63) / 64;
#pragma unroll
  for (int hm = 0; hm < NHM; ++hm) {
    if (hm) __syncthreads();
    constexpr int span = 4;
#pragma unroll
    for (int mo = 0; mo < span; ++mo) {
      int mt = hm*4 + mo;
      if (mt >= MT) break;
#pragma unroll
      for (int nt = 0; nt < 2; ++nt)
#pragma unroll
        for (int j = 0; j < 4; ++j) {
          int m2 = mo*16 + rq*4 + j;
          int cl = wid*32 + nt*16 + rr;
          ep[m2*128 + (cl ^ ((m2 & 7) << 2))] = acc[mt][nt][j];
        }
    }
    __syncthreads();
    if (STAGE < 3) {
      for (int it = tid; it < 64*16; it += 256) {
        int m2 = it >> 4, u8 = it & 15;
        int m = hm*64 + m2;
        if (m >= M) break;
        if (STAGE == 0 && m >= 66) break;
        if (STAGE == 2) { int cp = m >> 6; if (cp && (kw == 0 || kw == 32)) continue; }
        int swz = (m2 & 7) << 2;
        float4 v0 = *(const float4*)(ep + m2*128 + ((u8*8) ^ swz));
        float4 v1 = *(const float4*)(ep + m2*128 + ((u8*8 + 4) ^ swz));
        uint4 pw;
        pw.x = f2b(v0.x) | ((unsigned)f2b(v0.y) << 16);
        pw.y = f2b(v0.z) | ((unsigned)f2b(v0.w) << 16);
        pw.z = f2b(v1.x) | ((unsigned)f2b(v1.y) << 16);
        pw.w = f2b(v1.z) | ((unsigned)f2b(v1.w) << 16);
        size_t rowb;
        if (STAGE == 0) rowb = ((size_t)(b*64 + h)*66 + m)*384 + c0;
        else if (STAGE == 1) { int cp = m >> 6, kh = m & 63;
          rowb = (((size_t)((b*2 + cp)*64 + kh)*33) + kw)*384 + c0; }
        else { int cp = m >> 6, h2 = m & 63; int kp = cp ? 32 + kw : kw;
          rowb = ((size_t)(b*64 + kp)*64 + h2)*384 + c0; }
        *(uint4*)(O + rowb + u8*8) = pw;
      }
    } else {
      for (int it = tid; it < 64*32; it += 256) {
        int m = it >> 5, u = it & 31;
        int swz = (m & 7) << 2;
        float4 v = *(const float4*)(ep + m*128 + ((u*4) ^ swz));
        size_t idx = ((size_t)(b*64 + h)*64 + m)*384 + c0 + u*4;
        float4 rx = *(const float4*)(xres + idx);
        float4 ov;
        ov.x = v.x + rx.x + b2[c0 + u*4 + 0];
        ov.y = v.y + rx.y + b2[c0 + u*4 + 1];
        ov.z = v.z + rx.z + b2[c0 + u*4 + 2];
        ov.w = v.w + rx.w + b2[c0 + u*4 + 3];
        *(float4*)(outp + idx) = ov;
      }
      for (int it = tid; it < 64*16; it += 256) {
        int m = it >> 4, u8 = it & 15;
        int swz = (m & 7) << 2;
        float4 v0 = *(const float4*)(ep + m*128 + ((u8*8) ^ swz));
        float4 v1 = *(const float4*)(ep + m*128 + ((u8*8 + 4) ^ swz));
        uint4 pw;
        pw.x = f2b(v0.x) | ((unsigned)f2b(v0.y) << 16);
        pw.y = f2b(v0.z) | ((unsigned)f2b(v0.w) << 16);
        pw.z = f2b(v1.x) | ((unsigned)f2b(v1.y) << 16);
        pw.w = f2b(v1.z) | ((unsigned)f2b(v1.w) << 16);
        *(uint4*)(xsb + ((size_t)(b*64 + h)*64 + m)*384 + c0 + u8*8) = pw;
      }
    }
  }
}

// ---------------- per-mode block-diag complex matmul + bias + split ReLU -------
__global__ __launch_bounds__(384) void blockmm2_kernel(
    const unsigned short* __restrict__ S2, const float* __restrict__ w1,
    const float* __restrict__ b1, unsigned short* __restrict__ o1) {
  int bid = blockIdx.x;
  int n = bid % NBK;
  int kw = (bid / NBK) % WF;
  int h = bid / (NBK*WF);
  int tid = threadIdx.x;
  __shared__ float2 wl[BSZ*BSZ];
  __shared__ float2 xl2[BB][BSZ];
  __shared__ float2 bl[BSZ];
  const float2* wbase = (const float2*)w1 + ((size_t)(h*WF + kw)*NBK + n)*(BSZ*BSZ);
  for (int t = tid; t < BSZ*BSZ; t += 384) wl[t] = wbase[t];
  const float2* bbase = (const float2*)b1 + ((size_t)(h*WF + kw)*NBK + n)*BSZ;
  if (tid < BSZ) bl[tid] = bbase[tid];
  {
    int bb = tid / BSZ, i = tid % BSZ;
    size_t ir = (((size_t)((bb*2 + 0)*64 + h)*33) + kw)*384 + n*48 + i;
    size_t ii = (((size_t)((bb*2 + 1)*64 + h)*33) + kw)*384 + n*48 + i;
    xl2[bb][i] = make_float2(b2fl(S2[ir]), b2fl(S2[ii]));
  }
  __syncthreads();
  int bb = tid / BSZ, o = tid % BSZ;
  float2 acc = bl[o];
#pragma unroll
  for (int i = 0; i < BSZ; ++i) {
    float2 xv = xl2[bb][i];
    float2 wv = wl[i*BSZ + o];
    acc.x += xv.x*wv.x - xv.y*wv.y;
    acc.y += xv.x*wv.y + xv.y*wv.x;
  }
  size_t idr = (((size_t)((bb*2 + 0)*33) + kw)*64 + h)*384 + n*48 + o;
  size_t idi = (((size_t)((bb*2 + 1)*33) + kw)*64 + h)*384 + n*48 + o;
  o1[idr] = f2b(fmaxf(acc.x, 0.f));
  o1[idi] = f2b(fmaxf(acc.y, 0.f));
}

// ---------------- LN2: bf16 in -> bf16 out -------------------------------------
__global__ __launch_bounds__(256) void ln2_kernel(const unsigned short* __restrict__ in,
    const float* __restrict__ g, const float* __restrict__ bsh,
    unsigned short* __restrict__ outp) {
  int token = blockIdx.x * 4 + (threadIdx.x >> 6);
  int lane = threadIdx.x & 63;
  const unsigned short* row = in + (size_t)token * CC;
  float v[6]; float s = 0.f;
#pragma unroll
  for (int j = 0; j < 6; ++j) { v[j] = b2fl(row[lane + 64*j]); s += v[j]; }
#pragma unroll
  for (int off = 32; off >= 1; off >>= 1) s += __shfl_xor(s, off);
  float mu = s * (1.0f/CC);
  float q = 0.f;
#pragma unroll
  for (int j = 0; j < 6; ++j) { float d = v[j] - mu; q += d*d; }
#pragma unroll
  for (int off = 32; off >= 1; off >>= 1) q += __shfl_xor(q, off);
  float rs = rsqrtf(q * (1.0f/CC) + 1e-5f);
#pragma unroll
  for (int j = 0; j < 6; ++j) {
    int c = lane + 64*j;
    outp[(size_t)token*CC + c] = f2b((v[j]-mu)*rs*g[c] + bsh[c]);
  }
}

// ---------------- transpose + fp32->bf16 convert (weights) ---------------------
__global__ __launch_bounds__(256) void convtr_kernel(const float* __restrict__ in,
    unsigned short* __restrict__ out, int R, int C) {
  __shared__ float tile[32][33];
  int ntc = C >> 5;
  int bx = blockIdx.x % ntc;
  int by = blockIdx.x / ntc;
  int tx = threadIdx.x & 31, ty = threadIdx.x >> 5;
  for (int rr2 = ty; rr2 < 32; rr2 += 8)
    tile[rr2][tx] = in[(size_t)(by*32+rr2)*C + bx*32 + tx];
  __syncthreads();
  for (int rr2 = ty; rr2 < 32; rr2 += 8)
    out[(size_t)(bx*32+rr2)*R + by*32 + tx] = f2b(tile[tx][rr2]);
}

// ---------------- bf16 MFMA GEMM (MLP), BK=64, XOR-swizzled LDS ----------------
template<int GELU, int OUTBF16>
__global__ __launch_bounds__(256) void mfma_gemm_kernel(
    const unsigned short* __restrict__ A, int lda,
    const unsigned short* __restrict__ BT, int ldbt,
    const float* __restrict__ bias,
    void* __restrict__ Cp, int ldc, int K, int ntn) {
  __shared__ __align__(16) unsigned short gsm[128*64*2];  // As 16KB + Bs 16KB
  unsigned short* As = gsm;
  unsigned short* Bs = gsm + 128*64;
  int bn = blockIdx.x % ntn;
  int bm = blockIdx.x / ntn;
  int t = threadIdx.x;
  int lane = t & 63;
  int wid = t >> 6;
  int wm = wid >> 1, wn = wid & 1;
  int rr = lane & 15, rq = lane >> 4;

  f32x4 acc[4][4];
#pragma unroll
  for (int m = 0; m < 4; ++m)
#pragma unroll
    for (int n = 0; n < 4; ++n) acc[m][n] = (f32x4){0.f,0.f,0.f,0.f};

  const unsigned short* Abase = A + (size_t)bm*128*lda;
  const unsigned short* Bbase = BT + (size_t)bn*128*ldbt;

  for (int k0 = 0; k0 < K; k0 += 64) {
#pragma unroll
    for (int i = 0; i < 4; ++i) {
      int idx = t + i*256;
      int row = idx >> 3, ch = idx & 7;
      gload16(Abase + (size_t)row*lda + k0 + ((ch ^ (row & 7)) << 3),
              (char*)As + i*4096 + wid*1024);
    }
#pragma unroll
    for (int i = 0; i < 4; ++i) {
      int idx = t + i*256;
      int row = idx >> 3, ch = idx & 7;
      gload16(Bbase + (size_t)row*ldbt + k0 + ((ch ^ (row & 7)) << 3),
              (char*)Bs + i*4096 + wid*1024);
    }
    __syncthreads();
#pragma unroll
    for (int ks = 0; ks < 2; ++ks) {
      int chb = ks*4 + rq;
      bf16x8 af[4], bfr[4];
#pragma unroll
      for (int m = 0; m < 4; ++m) {
        int row = wm*64 + m*16 + rr;
        af[m] = *(const bf16x8*)((const char*)As + row*128 + ((chb ^ (row & 7)) << 4));
      }
#pragma unroll
      for (int n = 0; n < 4; ++n) {
        int row = wn*64 + n*16 + rr;
        bfr[n] = *(const bf16x8*)((const char*)Bs + row*128 + ((chb ^ (row & 7)) << 4));
      }
#pragma unroll
      for (int m = 0; m < 4; ++m)
#pragma unroll
        for (int n = 0; n < 4; ++n)
          acc[m][n] = __builtin_amdgcn_mfma_f32_16x16x32_bf16(af[m], bfr[n], acc[m][n], 0, 0, 0);
    }
    __syncthreads();
  }

  if (OUTBF16) {
    // repack via LDS (32 KB), coalesced uint4 stores
    unsigned short* ep = gsm;
#pragma unroll
    for (int m = 0; m < 4; ++m)
#pragma unroll
      for (int n = 0; n < 4; ++n)
#pragma unroll
        for (int j = 0; j < 4; ++j) {
          int row = wm*64 + m*16 + rq*4 + j;
          int col = wn*64 + n*16 + rr;
          float v = acc[m][n][j];
          if (GELU) {
            v += bias[bn*128 + col];
            v = 0.5f*v*(1.f + erff(v*0.70710678118654752f));
          }
          ep[row*128 + (col ^ ((row & 7) << 3))] = f2b(v);
        }
    __syncthreads();
    for (int it = t; it < 128*16; it += 256) {
      int m = it >> 4, u8 = it & 15;
      uint4 pw = *(const uint4*)(ep + m*128 + ((u8*8) ^ ((m & 7) << 3)));
      *(uint4*)((unsigned short*)Cp + (size_t)(bm*128 + m)*ldc + bn*128 + u8*8) = pw;
    }
  } else {
#pragma unroll
    for (int m = 0; m < 4; ++m) {
#pragma unroll
      for (int n = 0; n < 4; ++n) {
        int grow0 = bm*128 + wm*64 + m*16 + rq*4;
        int gcol  = bn*128 + wn*64 + n*16 + rr;
#pragma unroll
        for (int j = 0; j < 4; ++j) {
          float v = acc[m][n][j];
          if (GELU) { v += bias[gcol]; v = 0.5f*v*(1.f + erff(v*0.70710678118654752f)); }
          ((float*)Cp)[(size_t)(grow0+j)*ldc + gcol] += v;
        }
      }
    }
  }
}

extern "C" void kernel_launch(void* const* d_in, const int* in_sizes, int n_in,
                              void* d_out, int out_size, void* d_ws, size_t ws_size,
                              hipStream_t stream) {
  const float* x   = (const float*)d_in[0];
  const float* w1  = (const float*)d_in[1];
  const float* b1  = (const float*)d_in[2];
  const float* n1w = (const float*)d_in[3];
  const float* n1b = (const float*)d_in[4];
  const float* n2w = (const float*)d_in[5];
  const float* n2b = (const float*)d_in[6];
  const float* mw1 = (const float*)d_in[7];
  const float* mb1 = (const float*)d_in[8];
  const float* mw2 = (const float*)d_in[9];
  const float* mb2 = (const float*)d_in[10];
  float* out = (float*)d_out;

  char* ws = (char*)d_ws;
  const size_t MB = 1ull << 20;
  unsigned short* xn  = (unsigned short*)(ws + 0*MB);    // 25.2 MB [b,h,c,w]
  unsigned short* S1  = (unsigned short*)(ws + 26*MB);   // 26 [b,h,m66,c]
  unsigned short* S2  = (unsigned short*)(ws + 53*MB);   // 26 [b2cp,kh,kw,c]
  unsigned short* o1  = (unsigned short*)(ws + 80*MB);   // 26 [b2cp,kw,h,c]
  unsigned short* S3  = (unsigned short*)(ws + 107*MB);  // 25.2 [b,kp,h,c]
  unsigned short* xsb = (unsigned short*)(ws + 133*MB);  // 25.2 bf16 xs
  unsigned short* xmb = (unsigned short*)(ws + 159*MB);  // 25.2 bf16 LN2 out
  unsigned short* hid = (unsigned short*)(ws + 185*MB);  // 100.7 bf16
  unsigned short* w1t = (unsigned short*)(ws + 286*MB);
  unsigned short* w2t = (unsigned short*)(ws + 288*MB);
  unsigned short* atab = (unsigned short*)(ws + 290*MB);

  init_tw<<<64, 256, 0, stream>>>(atab);
  convtr_kernel<<<(384/32)*(1536/32), 256, 0, stream>>>(mw1, w1t, 384, 1536);
  convtr_kernel<<<(1536/32)*(384/32), 256, 0, stream>>>(mw2, w2t, 1536, 384);

  // LN1 + transpose -> bf16
  ln1t_kernel<<<512, 256, 0, stream>>>(x, n1w, n1b, xn);
  // W-fwd
  dft_kernel<0><<<512*3, 256, 0, stream>>>(atab, xn, S1, nullptr, nullptr, nullptr, nullptr);
  // H-fwd
  dft_kernel<1><<<264*3, 256, 0, stream>>>(atab, S1, S2, nullptr, nullptr, nullptr, nullptr);
  // block-diag complex matmul + ReLU
  blockmm2_kernel<<<64*WF*NBK, 384, 0, stream>>>(S2, w1, b1, o1);
  // H-inv
  dft_kernel<2><<<264*3, 256, 0, stream>>>(atab, o1, S3, nullptr, nullptr, nullptr, nullptr);
  // W-inv + residual + xs(bf16)
  dft_kernel<3><<<512*3, 256, 0, stream>>>(atab, S3, nullptr, x, mb2, xsb, out);
  // LN2
  ln2_kernel<<<NTOK/4, 256, 0, stream>>>(xsb, n2w, n2b, xmb);
  // GEMM1: hid = gelu(xm @ W1 + b1)  M=32768 N=1536 K=384
  mfma_gemm_kernel<1,1><<<256*12, 256, 0, stream>>>(xmb, 384, w1t, 384, mb1,
                                                    hid, 1536, 384, 12);
  // GEMM2: out += hid @ W2  M=32768 N=384 K=1536
  mfma_gemm_kernel<0,0><<<256*3, 256, 0, stream>>>(hid, 1536, w2t, 1536, nullptr,
                                                   out, 384, 1536, 3);
}

// Round 6
// 386.311 us; speedup vs baseline: 4.7608x; 1.0527x over previous
//
#include <hip/hip_runtime.h>
#include <math.h>

// AFNO block, MI355X. Spectral path: bf16 MFMA DFT stages vs constant twiddle
// tables. MLP: bf16 MFMA GEMMs (XOR-swizzled LDS, XCD-swizzled grid).
// LN1 fused w/ transpose; residual+bias fused into GEMM2 epilogue.

#define BB 8
#define CC 384
#define WF 33
#define NBK 8
#define BSZ 48
#define NTOK 32768
#define TW64 0.09817477042468103f  // 2*pi/64

// twiddle table element offsets (bf16)
#define T_AWF 0
#define T_AHF 5120
#define T_AHI 21504
#define T_AWI 37888

typedef __attribute__((ext_vector_type(8))) short bf16x8;
typedef __attribute__((ext_vector_type(4))) float f32x4;

__device__ __forceinline__ unsigned short f2b(float f) {
  union { float f; unsigned u; } x; x.f = f;
  unsigned u = x.u;
  return (unsigned short)((u + 0x7fffu + ((u >> 16) & 1u)) >> 16);
}
__device__ __forceinline__ float b2fl(unsigned short u) {
  return __uint_as_float(((unsigned)u) << 16);
}
__device__ __forceinline__ void gload16(const void* g, void* l) {
  __builtin_amdgcn_global_load_lds(
      (const __attribute__((address_space(1))) void*)g,
      (__attribute__((address_space(3))) void*)l, 16, 0, 0);
}

// ---------------- prep: twiddle tables + weight transposes (one kernel) --------
__global__ __launch_bounds__(256) void prep_kernel(unsigned short* __restrict__ A,
    const float* __restrict__ mw1, unsigned short* __restrict__ w1t,
    const float* __restrict__ mw2, unsigned short* __restrict__ w2t) {
  __shared__ float tile[32][33];
  int bid = blockIdx.x;
  if (bid < 64) {
    int idx0 = bid * 256 + threadIdx.x;
    const float S = 0.125f;
    for (int e = idx0; e < 5120; e += 16384) {
      int m = e >> 6, w = e & 63;
      float val = 0.f;
      if (m < 66) {
        int kwv = m >> 1;
        float th = (float)((kwv * w) & 63) * TW64;
        val = (m & 1) ? (((kwv==0)||(kwv==32)) ? 0.f : -sinf(th)*S) : cosf(th)*S;
      }
      A[T_AWF + e] = f2b(val);
    }
    for (int e = idx0; e < 16384; e += 16384) {
      int comp = e >> 13; int r = e & 8191; int mp = r >> 6, hh = r & 63;
      int cpo = mp >> 6, kh = mp & 63;
      float th = (float)((kh * hh) & 63) * TW64;
      float cv = cosf(th), sv = sinf(th);
      float fv = (cpo == 0) ? (comp == 0 ? cv : sv) : (comp == 0 ? -sv : cv);
      A[T_AHF + e] = f2b(fv * S);
      float iv = (cpo == 0) ? (comp == 0 ? cv : -sv) : (comp == 0 ? sv : cv);
      A[T_AHI + e] = f2b(iv * S);
    }
    for (int e = idx0; e < 4096; e += 16384) {
      int w = e >> 6, kp = e & 63;
      float val;
      if (kp <= 32) {
        float th = (float)((kp * w) & 63) * TW64;
        val = cosf(th) * (((kp==0)||(kp==32)) ? 1.f : 2.f) * S;
      } else {
        int k2 = kp - 32;
        float th = (float)((k2 * w) & 63) * TW64;
        val = -2.f * sinf(th) * S;
      }
      A[T_AWI + e] = f2b(val);
    }
    return;
  }
  // transpose+convert: bid 64..639 -> mw1 (384x1536), 640..1215 -> mw2 (1536x384)
  const float* in; unsigned short* outb; int R, C, tb;
  if (bid < 640) { in = mw1; outb = w1t; R = 384; C = 1536; tb = bid - 64; }
  else           { in = mw2; outb = w2t; R = 1536; C = 384; tb = bid - 640; }
  int ntc = C >> 5;
  int bx = tb % ntc;
  int by = tb / ntc;
  int tx = threadIdx.x & 31, ty = threadIdx.x >> 5;
  for (int rr2 = ty; rr2 < 32; rr2 += 8)
    tile[rr2][tx] = in[(size_t)(by*32+rr2)*C + bx*32 + tx];
  __syncthreads();
  for (int rr2 = ty; rr2 < 32; rr2 += 8)
    outb[(size_t)(bx*32+rr2)*R + by*32 + tx] = f2b(tile[tx][rr2]);
}

// ---------------- LN1 fused with transpose: x[b,h,w,c] -> xn[b,h,c,w] bf16 -----
__global__ __launch_bounds__(256) void ln1t_kernel(const float* __restrict__ x,
    const float* __restrict__ g, const float* __restrict__ be,
    unsigned short* __restrict__ xn) {
  int outer = blockIdx.x;  // b*64+h
  int tid = threadIdx.x, lane = tid & 63, wg = tid >> 6;
  const float* base = x + (size_t)outer * 64 * 384;
  float s[16], s2[16];
#pragma unroll
  for (int q = 0; q < 16; ++q) { s[q] = 0.f; s2[q] = 0.f; }
  for (int ch = 0; ch < 6; ++ch) {
#pragma unroll
    for (int q = 0; q < 16; ++q) {
      float v = base[(size_t)(wg*16 + q)*384 + ch*64 + lane];
      s[q] += v; s2[q] += v*v;
    }
  }
#pragma unroll
  for (int q = 0; q < 16; ++q) {
#pragma unroll
    for (int off = 32; off >= 1; off >>= 1) {
      s[q] += __shfl_xor(s[q], off);
      s2[q] += __shfl_xor(s2[q], off);
    }
  }
  float mu[16], rs[16];
#pragma unroll
  for (int q = 0; q < 16; ++q) {
    mu[q] = s[q] * (1.f/384.f);
    rs[q] = rsqrtf(s2[q] * (1.f/384.f) - mu[q]*mu[q] + 1e-5f);
  }
  unsigned short* o = xn + (size_t)outer * 384 * 64;
  for (int ch = 0; ch < 6; ++ch) {
    int c = ch*64 + lane;
    float ga = g[c], bb2 = be[c];
#pragma unroll
    for (int qq = 0; qq < 4; ++qq) {
      unsigned short hv[4];
#pragma unroll
      for (int r2 = 0; r2 < 4; ++r2) {
        int q = qq*4 + r2;
        hv[r2] = f2b((base[(size_t)(wg*16+q)*384 + c]-mu[q])*rs[q]*ga + bb2);
      }
      uint2 pw;
      pw.x = hv[0] | ((unsigned)hv[1] << 16);
      pw.y = hv[2] | ((unsigned)hv[3] << 16);
      *(uint2*)(o + (size_t)c*64 + wg*16 + qq*4) = pw;
    }
  }
}

// ---------------- DFT stage as MFMA GEMM (single bf16 plane) -------------------
// STAGE: 0=W-fwd, 1=H-fwd, 2=H-inv, 3=W-inv (all write bf16 to O)
template<int STAGE>
__global__ __launch_bounds__(256) void dft_kernel(
    const unsigned short* __restrict__ A0, const unsigned short* __restrict__ D,
    unsigned short* __restrict__ O) {
  constexpr int M = (STAGE==0) ? 80 : (STAGE==3) ? 64 : 128;
  constexpr int MT = M / 16;
  constexpr int NA = (STAGE==1 || STAGE==2) ? 2 : 1;
  constexpr int ABYTES = NA * M * 128;
  constexpr int STG = ABYTES + 16384;
  constexpr int EPB = 64 * 128 * 4;       // 32 KB half-epilogue
  constexpr int SB = (STG > EPB) ? STG : EPB;
  __shared__ __align__(16) char smem[SB];
  char* BPL = smem + ABYTES;              // B plane, 16 KB

  int bid = blockIdx.x;
  int cc = bid % 3; int outer = bid / 3;
  int c0 = cc * 128;
  int tid = threadIdx.x, lane = tid & 63, wid = tid >> 6;
  int rr = lane & 15, rq = lane >> 4;
  int b, h = 0, kw = 0;
  if (STAGE == 0 || STAGE == 3) { b = outer >> 6; h = outer & 63; }
  else { b = outer / 33; kw = outer % 33; }

  f32x4 acc[MT][2];
#pragma unroll
  for (int mt = 0; mt < MT; ++mt)
#pragma unroll
    for (int nt = 0; nt < 2; ++nt) acc[mt][nt] = (f32x4){0.f,0.f,0.f,0.f};

  // ---- stage A tables (all comps), 16B-chunk XOR source pre-swizzle ----
  const unsigned short* Atab =
    (STAGE==0) ? A0+T_AWF : (STAGE==1) ? A0+T_AHF : (STAGE==2) ? A0+T_AHI : A0+T_AWI;
  constexpr int ACH = NA * M * 8;  // 16B chunks
#pragma unroll
  for (int i = 0; i < (ACH + 255)/256; ++i) {
    int t2 = tid + i*256;
    if ((ACH % 256 == 0) || (t2 < ACH)) {
      int mm = t2 >> 3, ch = t2 & 7;
      gload16(Atab + mm*64 + ((ch ^ (mm & 7)) << 3), smem + i*4096 + wid*1024);
    }
  }

  int ncomp = (STAGE == 1) ? ((kw == 0 || kw == 32) ? 1 : 2) : NA;

  for (int comp = 0; comp < ncomp; ++comp) {
    if (comp) __syncthreads();
    // ---- stage B tile [c 128][k 64] bf16 ----
    if (STAGE == 0) {
      const unsigned short* src = D + (((size_t)(b*64 + h))*384 + c0) * 64;
#pragma unroll
      for (int i = 0; i < 4; ++i) {
        int idx = tid + i*256;
        int c = idx >> 3, ch = idx & 7;
        gload16(src + c*64 + ((ch ^ (c & 7)) << 3), BPL + i*4096 + wid*1024);
      }
    } else {
      size_t P; int RS;
      if (STAGE == 1) { P = (size_t)b*(64*66*384) + (size_t)(2*kw + comp)*384 + c0; RS = 66*384; }
      else if (STAGE == 2) { P = ((size_t)((b*2 + comp)*33) + kw)*64*384 + c0; RS = 384; }
      else { P = (size_t)b*(64*64*384) + (size_t)h*384 + c0; RS = 64*384; }
      const unsigned short* p0 = D + P;
#pragma unroll
      for (int i = 0; i < 4; ++i) {
        int kq = (tid >> 6) + i*4;         // 0..15, 4 k each
        int c2 = (tid & 63) * 2;
        const unsigned short* p = p0 + (size_t)(4*kq)*RS + c2;
        unsigned u0 = *(const unsigned*)p;
        unsigned u1 = *(const unsigned*)(p + RS);
        unsigned u2 = *(const unsigned*)(p + 2*(size_t)RS);
        unsigned u3 = *(const unsigned*)(p + 3*(size_t)RS);
        uint2 w0, w1v;
        w0.x = (u0 & 0xffffu) | (u1 << 16);
        w0.y = (u2 & 0xffffu) | (u3 << 16);
        w1v.x = (u0 >> 16) | (u1 & 0xffff0000u);
        w1v.y = (u2 >> 16) | (u3 & 0xffff0000u);
        *(uint2*)(BPL + c2*128 + ((kq*8) ^ ((c2 & 7) << 4))) = w0;
        *(uint2*)(BPL + (c2+1)*128 + ((kq*8) ^ (((c2+1) & 7) << 4))) = w1v;
      }
    }
    __syncthreads();
    // ---- MFMA ----
#pragma unroll
    for (int kh2 = 0; kh2 < 2; ++kh2) {
      int chb = kh2*4 + rq;                // 16B chunk index 0..7
      bf16x8 bfr[2];
#pragma unroll
      for (int nt = 0; nt < 2; ++nt) {
        int n = wid*32 + nt*16 + rr;
        bfr[nt] = *(const bf16x8*)(BPL + n*128 + ((chb ^ (n & 7)) << 4));
      }
#pragma unroll
      for (int mt = 0; mt < MT; ++mt) {
        int mr = mt*16 + rr;
        bf16x8 af = *(const bf16x8*)(smem + comp*(M*128) + mr*128 + ((chb ^ (mr & 7)) << 4));
#pragma unroll
        for (int nt = 0; nt < 2; ++nt)
          acc[mt][nt] = __builtin_amdgcn_mfma_f32_16x16x32_bf16(af, bfr[nt], acc[mt][nt], 0, 0, 0);
      }
    }
  }
  __syncthreads();

  // ---- epilogue in 64-row halves: repack fp32 -> LDS (XOR swz), coalesced out
  float* ep = (float*)smem;
  constexpr int NHM = (M + 63) / 64;
#pragma unroll
  for (int hm = 0; hm < NHM; ++hm) {
    if (hm) __syncthreads();
#pragma unroll
    for (int mo = 0; mo < 4; ++mo) {
      int mt = hm*4 + mo;
      if (mt >= MT) break;
#pragma unroll
      for (int nt = 0; nt < 2; ++nt)
#pragma unroll
        for (int j = 0; j < 4; ++j) {
          int m2 = mo*16 + rq*4 + j;
          int cl = wid*32 + nt*16 + rr;
          ep[m2*128 + (cl ^ ((m2 & 7) << 2))] = acc[mt][nt][j];
        }
    }
    __syncthreads();
    for (int it = tid; it < 64*16; it += 256) {
      int m2 = it >> 4, u8 = it & 15;
      int m = hm*64 + m2;
      if (m >= M) break;
      if (STAGE == 0 && m >= 66) break;
      if (STAGE == 2) { int cp = m >> 6; if (cp && (kw == 0 || kw == 32)) continue; }
      int swz = (m2 & 7) << 2;
      float4 v0 = *(const float4*)(ep + m2*128 + ((u8*8) ^ swz));
      float4 v1 = *(const float4*)(ep + m2*128 + ((u8*8 + 4) ^ swz));
      uint4 pw;
      pw.x = f2b(v0.x) | ((unsigned)f2b(v0.y) << 16);
      pw.y = f2b(v0.z) | ((unsigned)f2b(v0.w) << 16);
      pw.z = f2b(v1.x) | ((unsigned)f2b(v1.y) << 16);
      pw.w = f2b(v1.z) | ((unsigned)f2b(v1.w) << 16);
      size_t rowb;
      if (STAGE == 0) rowb = ((size_t)(b*64 + h)*66 + m)*384 + c0;
      else if (STAGE == 1) { int cp = m >> 6, kh = m & 63;
        rowb = (((size_t)((b*2 + cp)*64 + kh)*33) + kw)*384 + c0; }
      else if (STAGE == 2) { int cp = m >> 6, h2 = m & 63; int kp = cp ? 32 + kw : kw;
        rowb = ((size_t)(b*64 + kp)*64 + h2)*384 + c0; }
      else rowb = ((size_t)(b*64 + h)*64 + m)*384 + c0;
      *(uint4*)(O + rowb + u8*8) = pw;
    }
  }
}

// ---------------- block-diag complex matmul + ReLU: 2 modes/block --------------
__global__ __launch_bounds__(384) void blockmm2_kernel(
    const unsigned short* __restrict__ S2, const float* __restrict__ w1,
    const float* __restrict__ b1, unsigned short* __restrict__ o1) {
  int bid = blockIdx.x;
  int np = bid % 4;                 // mode pair
  int kw = (bid / 4) % WF;
  int h = bid / (4*WF);
  int tid = threadIdx.x;
  __shared__ float4 wl4[2][48*24];  // [sub][i*24+o2] = (w[i][2o2], w[i][2o2+1])
  __shared__ float2 xl[2][BB][48];
  __shared__ float2 bl[2][48];
  // stage weights (float4 = 2 complex)
#pragma unroll
  for (int e = tid; e < 2304; e += 384) {
    int sub = e / 1152, r = e % 1152;
    const float4* wb4 = (const float4*)(w1 + ((size_t)((h*WF + kw)*NBK) + 2*np + sub)*(BSZ*BSZ*2));
    wl4[sub][r] = wb4[r];
  }
  if (tid < 96) {
    int sub = tid / 48, o = tid % 48;
    bl[sub][o] = ((const float2*)b1)[((size_t)((h*WF + kw)*NBK) + 2*np + sub)*BSZ + o];
  }
#pragma unroll
  for (int e = tid; e < 768; e += 384) {
    int sub = e / 384, r = e % 384, bb = r / 48, i = r % 48;
    int n = 2*np + sub;
    size_t ir = (((size_t)((bb*2 + 0)*64 + h)*33) + kw)*384 + n*48 + i;
    size_t ii = (((size_t)((bb*2 + 1)*64 + h)*33) + kw)*384 + n*48 + i;
    xl[sub][bb][i] = make_float2(b2fl(S2[ir]), b2fl(S2[ii]));
  }
  __syncthreads();
  int sub = tid / 192, r = tid % 192, bb = r / 24, o2 = r % 24;
  float4 bv = *(const float4*)(&bl[sub][2*o2]);
  float2 a0 = make_float2(bv.x, bv.y);
  float2 a1 = make_float2(bv.z, bv.w);
#pragma unroll
  for (int i = 0; i < 48; ++i) {
    float2 xv = xl[sub][bb][i];
    float4 wv = wl4[sub][i*24 + o2];
    a0.x += xv.x*wv.x - xv.y*wv.y;
    a0.y += xv.x*wv.y + xv.y*wv.x;
    a1.x += xv.x*wv.z - xv.y*wv.w;
    a1.y += xv.x*wv.w + xv.y*wv.z;
  }
  int n = 2*np + sub;
  size_t idr = (((size_t)((bb*2 + 0)*33) + kw)*64 + h)*384 + n*48 + 2*o2;
  size_t idi = (((size_t)((bb*2 + 1)*33) + kw)*64 + h)*384 + n*48 + 2*o2;
  *(unsigned*)(o1 + idr) = f2b(fmaxf(a0.x, 0.f)) | ((unsigned)f2b(fmaxf(a1.x, 0.f)) << 16);
  *(unsigned*)(o1 + idi) = f2b(fmaxf(a0.y, 0.f)) | ((unsigned)f2b(fmaxf(a1.y, 0.f)) << 16);
}

// ---------------- LN2: bf16 in -> bf16 out -------------------------------------
__global__ __launch_bounds__(256) void ln2_kernel(const unsigned short* __restrict__ in,
    const float* __restrict__ g, const float* __restrict__ bsh,
    unsigned short* __restrict__ outp) {
  int token = blockIdx.x * 4 + (threadIdx.x >> 6);
  int lane = threadIdx.x & 63;
  const unsigned short* row = in + (size_t)token * CC;
  float v[6]; float s = 0.f;
#pragma unroll
  for (int j = 0; j < 6; ++j) { v[j] = b2fl(row[lane + 64*j]); s += v[j]; }
#pragma unroll
  for (int off = 32; off >= 1; off >>= 1) s += __shfl_xor(s, off);
  float mu = s * (1.0f/CC);
  float q = 0.f;
#pragma unroll
  for (int j = 0; j < 6; ++j) { float d = v[j] - mu; q += d*d; }
#pragma unroll
  for (int off = 32; off >= 1; off >>= 1) q += __shfl_xor(q, off);
  float rs = rsqrtf(q * (1.0f/CC) + 1e-5f);
#pragma unroll
  for (int j = 0; j < 6; ++j) {
    int c = lane + 64*j;
    outp[(size_t)token*CC + c] = f2b((v[j]-mu)*rs*g[c] + bsh[c]);
  }
}

// ---------------- bf16 MFMA GEMM (MLP), BK=64, XOR-swizzled LDS ----------------
// MODE 0: bf16 store with bias+GELU.  MODE 1: fp32 out = acc + xs + x + b2.
template<int MODE>
__global__ __launch_bounds__(256) void mfma_gemm_kernel(
    const unsigned short* __restrict__ A, int lda,
    const unsigned short* __restrict__ BT, int ldbt,
    const float* __restrict__ bias,
    void* __restrict__ Cp, int ldc, int K, int ntn,
    const unsigned short* __restrict__ xsb, const float* __restrict__ xres,
    const float* __restrict__ b2v) {
  __shared__ __align__(16) unsigned short gsm[128*64*2];  // As 16KB + Bs 16KB
  unsigned short* As = gsm;
  unsigned short* Bs = gsm + 128*64;
  // XCD-aware bijective swizzle (grid % 8 == 0)
  int nb = (int)gridDim.x;
  int bidx = (int)blockIdx.x;
  int bswz = (bidx & 7) * (nb >> 3) + (bidx >> 3);
  int bn = bswz % ntn;
  int bm = bswz / ntn;
  int t = threadIdx.x;
  int lane = t & 63;
  int wid = t >> 6;
  int wm = wid >> 1, wn = wid & 1;
  int rr = lane & 15, rq = lane >> 4;

  f32x4 acc[4][4];
#pragma unroll
  for (int m = 0; m < 4; ++m)
#pragma unroll
    for (int n = 0; n < 4; ++n) acc[m][n] = (f32x4){0.f,0.f,0.f,0.f};

  const unsigned short* Abase = A + (size_t)bm*128*lda;
  const unsigned short* Bbase = BT + (size_t)bn*128*ldbt;

  for (int k0 = 0; k0 < K; k0 += 64) {
#pragma unroll
    for (int i = 0; i < 4; ++i) {
      int idx = t + i*256;
      int row = idx >> 3, ch = idx & 7;
      gload16(Abase + (size_t)row*lda + k0 + ((ch ^ (row & 7)) << 3),
              (char*)As + i*4096 + wid*1024);
    }
#pragma unroll
    for (int i = 0; i < 4; ++i) {
      int idx = t + i*256;
      int row = idx >> 3, ch = idx & 7;
      gload16(Bbase + (size_t)row*ldbt + k0 + ((ch ^ (row & 7)) << 3),
              (char*)Bs + i*4096 + wid*1024);
    }
    __syncthreads();
#pragma unroll
    for (int ks = 0; ks < 2; ++ks) {
      int chb = ks*4 + rq;
      bf16x8 af[4], bfr[4];
#pragma unroll
      for (int m = 0; m < 4; ++m) {
        int row = wm*64 + m*16 + rr;
        af[m] = *(const bf16x8*)((const char*)As + row*128 + ((chb ^ (row & 7)) << 4));
      }
#pragma unroll
      for (int n = 0; n < 4; ++n) {
        int row = wn*64 + n*16 + rr;
        bfr[n] = *(const bf16x8*)((const char*)Bs + row*128 + ((chb ^ (row & 7)) << 4));
      }
#pragma unroll
      for (int m = 0; m < 4; ++m)
#pragma unroll
        for (int n = 0; n < 4; ++n)
          acc[m][n] = __builtin_amdgcn_mfma_f32_16x16x32_bf16(af[m], bfr[n], acc[m][n], 0, 0, 0);
    }
    __syncthreads();
  }

  if (MODE == 0) {
    // bias + GELU, bf16 store via LDS repack
    unsigned short* ep = gsm;
#pragma unroll
    for (int m = 0; m < 4; ++m)
#pragma unroll
      for (int n = 0; n < 4; ++n)
#pragma unroll
        for (int j = 0; j < 4; ++j) {
          int row = wm*64 + m*16 + rq*4 + j;
          int col = wn*64 + n*16 + rr;
          float v = acc[m][n][j];
          v += bias[bn*128 + col];
          v = 0.5f*v*(1.f + erff(v*0.70710678118654752f));
          ep[row*128 + (col ^ ((row & 7) << 3))] = f2b(v);
        }
    __syncthreads();
    for (int it = t; it < 128*16; it += 256) {
      int m = it >> 4, u8 = it & 15;
      uint4 pw = *(const uint4*)(ep + m*128 + ((u8*8) ^ ((m & 7) << 3)));
      *(uint4*)((unsigned short*)Cp + (size_t)(bm*128 + m)*ldc + bn*128 + u8*8) = pw;
    }
  } else {
    // out = acc + xs(bf16) + x + b2, fp32, via 2-half LDS repack
    float* ep = (float*)gsm;  // 32 KB = 64*128 fp32
#pragma unroll
    for (int half = 0; half < 2; ++half) {
      __syncthreads();
#pragma unroll
      for (int mo = 0; mo < 2; ++mo) {
        int m = half*2 + mo;
#pragma unroll
        for (int n = 0; n < 4; ++n)
#pragma unroll
          for (int j = 0; j < 4; ++j) {
            int lr = wm*32 + mo*16 + rq*4 + j;
            int col = wn*64 + n*16 + rr;
            ep[lr*128 + (col ^ ((lr & 7) << 2))] = acc[m][n][j];
          }
      }
      __syncthreads();
      for (int it = t; it < 64*32; it += 256) {
        int lr = it >> 5, u = it & 31;
        int swz = (lr & 7) << 2;
        float4 v = *(const float4*)(ep + lr*128 + ((u*4) ^ swz));
        int grow = bm*128 + (lr >> 5)*64 + (half*2 + ((lr >> 4) & 1))*16 + (lr & 15);
        int gcol = bn*128 + u*4;
        size_t idx = (size_t)grow*ldc + gcol;
        float4 xr = *(const float4*)(xres + idx);
        uint2 xsv = *(const uint2*)(xsb + idx);
        float4 bv = *(const float4*)(b2v + gcol);
        float4 ov;
        ov.x = v.x + xr.x + b2fl((unsigned short)(xsv.x & 0xffffu)) + bv.x;
        ov.y = v.y + xr.y + b2fl((unsigned short)(xsv.x >> 16)) + bv.y;
        ov.z = v.z + xr.z + b2fl((unsigned short)(xsv.y & 0xffffu)) + bv.z;
        ov.w = v.w + xr.w + b2fl((unsigned short)(xsv.y >> 16)) + bv.w;
        *(float4*)((float*)Cp + idx) = ov;
      }
    }
  }
}

extern "C" void kernel_launch(void* const* d_in, const int* in_sizes, int n_in,
                              void* d_out, int out_size, void* d_ws, size_t ws_size,
                              hipStream_t stream) {
  const float* x   = (const float*)d_in[0];
  const float* w1  = (const float*)d_in[1];
  const float* b1  = (const float*)d_in[2];
  const float* n1w = (const float*)d_in[3];
  const float* n1b = (const float*)d_in[4];
  const float* n2w = (const float*)d_in[5];
  const float* n2b = (const float*)d_in[6];
  const float* mw1 = (const float*)d_in[7];
  const float* mb1 = (const float*)d_in[8];
  const float* mw2 = (const float*)d_in[9];
  const float* mb2 = (const float*)d_in[10];
  float* out = (float*)d_out;

  char* ws = (char*)d_ws;
  const size_t MB = 1ull << 20;
  unsigned short* xn  = (unsigned short*)(ws + 0*MB);    // 25.2 MB [b,h,c,w]
  unsigned short* S1  = (unsigned short*)(ws + 26*MB);   // 26 [b,h,m66,c]
  unsigned short* S2  = (unsigned short*)(ws + 53*MB);   // 26 [b2cp,kh,kw,c]
  unsigned short* o1  = (unsigned short*)(ws + 80*MB);   // 26 [b2cp,kw,h,c]
  unsigned short* S3  = (unsigned short*)(ws + 107*MB);  // 25.2 [b,kp,h,c]
  unsigned short* xsb = (unsigned short*)(ws + 133*MB);  // 25.2 bf16 xs
  unsigned short* xmb = (unsigned short*)(ws + 159*MB);  // 25.2 bf16 LN2 out
  unsigned short* hid = (unsigned short*)(ws + 185*MB);  // 100.7 bf16
  unsigned short* w1t = (unsigned short*)(ws + 286*MB);
  unsigned short* w2t = (unsigned short*)(ws + 288*MB);
  unsigned short* atab = (unsigned short*)(ws + 290*MB);

  // prep: twiddle tables + weight convert/transpose
  prep_kernel<<<1216, 256, 0, stream>>>(atab, mw1, w1t, mw2, w2t);

  // LN1 + transpose -> bf16
  ln1t_kernel<<<512, 256, 0, stream>>>(x, n1w, n1b, xn);
  // W-fwd
  dft_kernel<0><<<512*3, 256, 0, stream>>>(atab, xn, S1);
  // H-fwd
  dft_kernel<1><<<264*3, 256, 0, stream>>>(atab, S1, S2);
  // block-diag complex matmul + ReLU (2 modes/block)
  blockmm2_kernel<<<64*WF*4, 384, 0, stream>>>(S2, w1, b1, o1);
  // H-inv
  dft_kernel<2><<<264*3, 256, 0, stream>>>(atab, o1, S3);
  // W-inv -> xs (bf16)
  dft_kernel<3><<<512*3, 256, 0, stream>>>(atab, S3, xsb);
  // LN2
  ln2_kernel<<<NTOK/4, 256, 0, stream>>>(xsb, n2w, n2b, xmb);
  // GEMM1: hid = gelu(xm @ W1 + b1)  M=32768 N=1536 K=384
  mfma_gemm_kernel<0><<<256*12, 256, 0, stream>>>(xmb, 384, w1t, 384, mb1,
                                                  hid, 1536, 384, 12,
                                                  nullptr, nullptr, nullptr);
  // GEMM2: out = hid @ W2 + xs + x + b2  M=32768 N=384 K=1536
  mfma_gemm_kernel<1><<<256*3, 256, 0, stream>>>(hid, 1536, w2t, 1536, nullptr,
                                                 out, 384, 1536, 3,
                                                 xsb, x, mb2);
}

// Round 7
// 385.591 us; speedup vs baseline: 4.7696x; 1.0019x over previous
//
#include <hip/hip_runtime.h>
#include <math.h>

// AFNO block, MI355X. Spectral path: bf16 MFMA DFT stages vs constant twiddle
// tables. MLP: bf16 MFMA GEMMs, 2-phase double-buffered BK=32 (T3 minimum
// recipe), LN2 folded algebraically into GEMM1 epilogue (stats + affine).
// LN1 fused w/ transpose; residual+bias fused into GEMM2 epilogue.

#define BB 8
#define CC 384
#define WF 33
#define NBK 8
#define BSZ 48
#define NTOK 32768
#define TW64 0.09817477042468103f  // 2*pi/64

// twiddle table element offsets (bf16)
#define T_AWF 0
#define T_AHF 5120
#define T_AHI 21504
#define T_AWI 37888

typedef __attribute__((ext_vector_type(8))) short bf16x8;
typedef __attribute__((ext_vector_type(4))) float f32x4;

__device__ __forceinline__ unsigned short f2b(float f) {
  union { float f; unsigned u; } x; x.f = f;
  unsigned u = x.u;
  return (unsigned short)((u + 0x7fffu + ((u >> 16) & 1u)) >> 16);
}
__device__ __forceinline__ float b2fl(unsigned short u) {
  return __uint_as_float(((unsigned)u) << 16);
}
__device__ __forceinline__ void gload16(const void* g, void* l) {
  __builtin_amdgcn_global_load_lds(
      (const __attribute__((address_space(1))) void*)g,
      (__attribute__((address_space(3))) void*)l, 16, 0, 0);
}

// ---------------- prep: twiddles + weight transposes + LN2 fold vectors --------
__global__ __launch_bounds__(256) void prep_kernel(unsigned short* __restrict__ A,
    const float* __restrict__ mw1, unsigned short* __restrict__ w1t,
    const float* __restrict__ mw2, unsigned short* __restrict__ w2t,
    const float* __restrict__ n2w, const float* __restrict__ n2b,
    const float* __restrict__ mb1, float2* __restrict__ gsbb) {
  __shared__ float tile[32][33];
  int bid = blockIdx.x;
  if (bid < 64) {
    int idx0 = bid * 256 + threadIdx.x;
    const float S = 0.125f;
    for (int e = idx0; e < 5120; e += 16384) {
      int m = e >> 6, w = e & 63;
      float val = 0.f;
      if (m < 66) {
        int kwv = m >> 1;
        float th = (float)((kwv * w) & 63) * TW64;
        val = (m & 1) ? (((kwv==0)||(kwv==32)) ? 0.f : -sinf(th)*S) : cosf(th)*S;
      }
      A[T_AWF + e] = f2b(val);
    }
    for (int e = idx0; e < 16384; e += 16384) {
      int comp = e >> 13; int r = e & 8191; int mp = r >> 6, hh = r & 63;
      int cpo = mp >> 6, kh = mp & 63;
      float th = (float)((kh * hh) & 63) * TW64;
      float cv = cosf(th), sv = sinf(th);
      float fv = (cpo == 0) ? (comp == 0 ? cv : sv) : (comp == 0 ? -sv : cv);
      A[T_AHF + e] = f2b(fv * S);
      float iv = (cpo == 0) ? (comp == 0 ? cv : -sv) : (comp == 0 ? sv : cv);
      A[T_AHI + e] = f2b(iv * S);
    }
    for (int e = idx0; e < 4096; e += 16384) {
      int w = e >> 6, kp = e & 63;
      float val;
      if (kp <= 32) {
        float th = (float)((kp * w) & 63) * TW64;
        val = cosf(th) * (((kp==0)||(kp==32)) ? 1.f : 2.f) * S;
      } else {
        int k2 = kp - 32;
        float th = (float)((k2 * w) & 63) * TW64;
        val = -2.f * sinf(th) * S;
      }
      A[T_AWI + e] = f2b(val);
    }
    return;
  }
  if (bid >= 1216) {
    // gs[n] = sum_k g[k] W1[k][n]; bb[n] = sum_k bln[k] W1[k][n] + mb1[n]
    int n0 = (bid - 1216) * 256 + threadIdx.x;
    if (n0 < 1536) {
      float gsv = 0.f, bbv = 0.f;
      for (int k = 0; k < 384; ++k) {
        float a = mw1[(size_t)k*1536 + n0];
        gsv += n2w[k]*a;
        bbv += n2b[k]*a;
      }
      gsbb[n0] = make_float2(gsv, bbv + mb1[n0]);
    }
    return;
  }
  // transpose+convert: 64..639 -> mw1 (384x1536, fold g), 640..1215 -> mw2
  const float* in; unsigned short* outb; int R, C, tb; bool fold;
  if (bid < 640) { in = mw1; outb = w1t; R = 384; C = 1536; tb = bid - 64; fold = true; }
  else           { in = mw2; outb = w2t; R = 1536; C = 384; tb = bid - 640; fold = false; }
  int ntc = C >> 5;
  int bx = tb % ntc;
  int by = tb / ntc;
  int tx = threadIdx.x & 31, ty = threadIdx.x >> 5;
  for (int rr2 = ty; rr2 < 32; rr2 += 8)
    tile[rr2][tx] = in[(size_t)(by*32+rr2)*C + bx*32 + tx];
  __syncthreads();
  float gv = fold ? n2w[by*32 + tx] : 1.f;
  for (int rr2 = ty; rr2 < 32; rr2 += 8)
    outb[(size_t)(bx*32+rr2)*R + by*32 + tx] = f2b(tile[tx][rr2] * gv);
}

// ---------------- LN1 fused with transpose: x[b,h,w,c] -> xn[b,h,c,w] bf16 -----
__global__ __launch_bounds__(256) void ln1t_kernel(const float* __restrict__ x,
    const float* __restrict__ g, const float* __restrict__ be,
    unsigned short* __restrict__ xn) {
  int outer = blockIdx.x;  // b*64+h
  int tid = threadIdx.x, lane = tid & 63, wg = tid >> 6;
  const float* base = x + (size_t)outer * 64 * 384;
  float s[16], s2[16];
#pragma unroll
  for (int q = 0; q < 16; ++q) { s[q] = 0.f; s2[q] = 0.f; }
  for (int ch = 0; ch < 6; ++ch) {
#pragma unroll
    for (int q = 0; q < 16; ++q) {
      float v = base[(size_t)(wg*16 + q)*384 + ch*64 + lane];
      s[q] += v; s2[q] += v*v;
    }
  }
#pragma unroll
  for (int q = 0; q < 16; ++q) {
#pragma unroll
    for (int off = 32; off >= 1; off >>= 1) {
      s[q] += __shfl_xor(s[q], off);
      s2[q] += __shfl_xor(s2[q], off);
    }
  }
  float mu[16], rs[16];
#pragma unroll
  for (int q = 0; q < 16; ++q) {
    mu[q] = s[q] * (1.f/384.f);
    rs[q] = rsqrtf(s2[q] * (1.f/384.f) - mu[q]*mu[q] + 1e-5f);
  }
  unsigned short* o = xn + (size_t)outer * 384 * 64;
  for (int ch = 0; ch < 6; ++ch) {
    int c = ch*64 + lane;
    float ga = g[c], bb2 = be[c];
#pragma unroll
    for (int qq = 0; qq < 4; ++qq) {
      unsigned short hv[4];
#pragma unroll
      for (int r2 = 0; r2 < 4; ++r2) {
        int q = qq*4 + r2;
        hv[r2] = f2b((base[(size_t)(wg*16+q)*384 + c]-mu[q])*rs[q]*ga + bb2);
      }
      uint2 pw;
      pw.x = hv[0] | ((unsigned)hv[1] << 16);
      pw.y = hv[2] | ((unsigned)hv[3] << 16);
      *(uint2*)(o + (size_t)c*64 + wg*16 + qq*4) = pw;
    }
  }
}

// ---------------- DFT stage as MFMA GEMM (single bf16 plane) -------------------
// STAGE: 0=W-fwd, 1=H-fwd, 2=H-inv, 3=W-inv (all write bf16 to O)
template<int STAGE>
__global__ __launch_bounds__(256) void dft_kernel(
    const unsigned short* __restrict__ A0, const unsigned short* __restrict__ D,
    unsigned short* __restrict__ O) {
  constexpr int M = (STAGE==0) ? 80 : (STAGE==3) ? 64 : 128;
  constexpr int MT = M / 16;
  constexpr int NA = (STAGE==1 || STAGE==2) ? 2 : 1;
  constexpr int ABYTES = NA * M * 128;
  constexpr int STG = ABYTES + 16384;
  constexpr int EPB = 64 * 128 * 4;       // 32 KB half-epilogue
  constexpr int SB = (STG > EPB) ? STG : EPB;
  __shared__ __align__(16) char smem[SB];
  char* BPL = smem + ABYTES;              // B plane, 16 KB

  int bid = blockIdx.x;
  int cc = bid % 3; int outer = bid / 3;
  int c0 = cc * 128;
  int tid = threadIdx.x, lane = tid & 63, wid = tid >> 6;
  int rr = lane & 15, rq = lane >> 4;
  int b, h = 0, kw = 0;
  if (STAGE == 0 || STAGE == 3) { b = outer >> 6; h = outer & 63; }
  else { b = outer / 33; kw = outer % 33; }

  f32x4 acc[MT][2];
#pragma unroll
  for (int mt = 0; mt < MT; ++mt)
#pragma unroll
    for (int nt = 0; nt < 2; ++nt) acc[mt][nt] = (f32x4){0.f,0.f,0.f,0.f};

  // ---- stage A tables (all comps), 16B-chunk XOR source pre-swizzle ----
  const unsigned short* Atab =
    (STAGE==0) ? A0+T_AWF : (STAGE==1) ? A0+T_AHF : (STAGE==2) ? A0+T_AHI : A0+T_AWI;
  constexpr int ACH = NA * M * 8;  // 16B chunks
#pragma unroll
  for (int i = 0; i < (ACH + 255)/256; ++i) {
    int t2 = tid + i*256;
    if ((ACH % 256 == 0) || (t2 < ACH)) {
      int mm = t2 >> 3, ch = t2 & 7;
      gload16(Atab + mm*64 + ((ch ^ (mm & 7)) << 3), smem + i*4096 + wid*1024);
    }
  }

  int ncomp = (STAGE == 1) ? ((kw == 0 || kw == 32) ? 1 : 2) : NA;

  for (int comp = 0; comp < ncomp; ++comp) {
    if (comp) __syncthreads();
    // ---- stage B tile [c 128][k 64] bf16 ----
    if (STAGE == 0) {
      const unsigned short* src = D + (((size_t)(b*64 + h))*384 + c0) * 64;
#pragma unroll
      for (int i = 0; i < 4; ++i) {
        int idx = tid + i*256;
        int c = idx >> 3, ch = idx & 7;
        gload16(src + c*64 + ((ch ^ (c & 7)) << 3), BPL + i*4096 + wid*1024);
      }
    } else {
      size_t P; int RS;
      if (STAGE == 1) { P = (size_t)b*(64*66*384) + (size_t)(2*kw + comp)*384 + c0; RS = 66*384; }
      else if (STAGE == 2) { P = ((size_t)((b*2 + comp)*33) + kw)*64*384 + c0; RS = 384; }
      else { P = (size_t)b*(64*64*384) + (size_t)h*384 + c0; RS = 64*384; }
      const unsigned short* p0 = D + P;
#pragma unroll
      for (int i = 0; i < 4; ++i) {
        int kq = (tid >> 6) + i*4;         // 0..15, 4 k each
        int c2 = (tid & 63) * 2;
        const unsigned short* p = p0 + (size_t)(4*kq)*RS + c2;
        unsigned u0 = *(const unsigned*)p;
        unsigned u1 = *(const unsigned*)(p + RS);
        unsigned u2 = *(const unsigned*)(p + 2*(size_t)RS);
        unsigned u3 = *(const unsigned*)(p + 3*(size_t)RS);
        uint2 w0, w1v;
        w0.x = (u0 & 0xffffu) | (u1 << 16);
        w0.y = (u2 & 0xffffu) | (u3 << 16);
        w1v.x = (u0 >> 16) | (u1 & 0xffff0000u);
        w1v.y = (u2 >> 16) | (u3 & 0xffff0000u);
        *(uint2*)(BPL + c2*128 + ((kq*8) ^ ((c2 & 7) << 4))) = w0;
        *(uint2*)(BPL + (c2+1)*128 + ((kq*8) ^ (((c2+1) & 7) << 4))) = w1v;
      }
    }
    __syncthreads();
    // ---- MFMA ----
#pragma unroll
    for (int kh2 = 0; kh2 < 2; ++kh2) {
      int chb = kh2*4 + rq;                // 16B chunk index 0..7
      bf16x8 bfr[2];
#pragma unroll
      for (int nt = 0; nt < 2; ++nt) {
        int n = wid*32 + nt*16 + rr;
        bfr[nt] = *(const bf16x8*)(BPL + n*128 + ((chb ^ (n & 7)) << 4));
      }
#pragma unroll
      for (int mt = 0; mt < MT; ++mt) {
        int mr = mt*16 + rr;
        bf16x8 af = *(const bf16x8*)(smem + comp*(M*128) + mr*128 + ((chb ^ (mr & 7)) << 4));
#pragma unroll
        for (int nt = 0; nt < 2; ++nt)
          acc[mt][nt] = __builtin_amdgcn_mfma_f32_16x16x32_bf16(af, bfr[nt], acc[mt][nt], 0, 0, 0);
      }
    }
  }
  __syncthreads();

  // ---- epilogue in 64-row halves: repack fp32 -> LDS (XOR swz), coalesced out
  float* ep = (float*)smem;
  constexpr int NHM = (M + 63) / 64;
#pragma unroll
  for (int hm = 0; hm < NHM; ++hm) {
    if (hm) __syncthreads();
#pragma unroll
    for (int mo = 0; mo < 4; ++mo) {
      int mt = hm*4 + mo;
      if (mt >= MT) break;
#pragma unroll
      for (int nt = 0; nt < 2; ++nt)
#pragma unroll
        for (int j = 0; j < 4; ++j) {
          int m2 = mo*16 + rq*4 + j;
          int cl = wid*32 + nt*16 + rr;
          ep[m2*128 + (cl ^ ((m2 & 7) << 2))] = acc[mt][nt][j];
        }
    }
    __syncthreads();
    for (int it = tid; it < 64*16; it += 256) {
      int m2 = it >> 4, u8 = it & 15;
      int m = hm*64 + m2;
      if (m >= M) break;
      if (STAGE == 0 && m >= 66) break;
      if (STAGE == 2) { int cp = m >> 6; if (cp && (kw == 0 || kw == 32)) continue; }
      int swz = (m2 & 7) << 2;
      float4 v0 = *(const float4*)(ep + m2*128 + ((u8*8) ^ swz));
      float4 v1 = *(const float4*)(ep + m2*128 + ((u8*8 + 4) ^ swz));
      uint4 pw;
      pw.x = f2b(v0.x) | ((unsigned)f2b(v0.y) << 16);
      pw.y = f2b(v0.z) | ((unsigned)f2b(v0.w) << 16);
      pw.z = f2b(v1.x) | ((unsigned)f2b(v1.y) << 16);
      pw.w = f2b(v1.z) | ((unsigned)f2b(v1.w) << 16);
      size_t rowb;
      if (STAGE == 0) rowb = ((size_t)(b*64 + h)*66 + m)*384 + c0;
      else if (STAGE == 1) { int cp = m >> 6, kh = m & 63;
        rowb = (((size_t)((b*2 + cp)*64 + kh)*33) + kw)*384 + c0; }
      else if (STAGE == 2) { int cp = m >> 6, h2 = m & 63; int kp = cp ? 32 + kw : kw;
        rowb = ((size_t)(b*64 + kp)*64 + h2)*384 + c0; }
      else rowb = ((size_t)(b*64 + h)*64 + m)*384 + c0;
      *(uint4*)(O + rowb + u8*8) = pw;
    }
  }
}

// ---------------- block-diag complex matmul + ReLU: 2 modes/block --------------
__global__ __launch_bounds__(384) void blockmm2_kernel(
    const unsigned short* __restrict__ S2, const float* __restrict__ w1,
    const float* __restrict__ b1, unsigned short* __restrict__ o1) {
  int bid = blockIdx.x;
  int np = bid % 4;                 // mode pair
  int kw = (bid / 4) % WF;
  int h = bid / (4*WF);
  int tid = threadIdx.x;
  __shared__ float4 wl4[2][48*24];  // [sub][i*24+o2] = (w[i][2o2], w[i][2o2+1])
  __shared__ float2 xl[2][BB][48];
  __shared__ float2 bl[2][48];
#pragma unroll
  for (int e = tid; e < 2304; e += 384) {
    int sub = e / 1152, r = e % 1152;
    const float4* wb4 = (const float4*)(w1 + ((size_t)((h*WF + kw)*NBK) + 2*np + sub)*(BSZ*BSZ*2));
    wl4[sub][r] = wb4[r];
  }
  if (tid < 96) {
    int sub = tid / 48, o = tid % 48;
    bl[sub][o] = ((const float2*)b1)[((size_t)((h*WF + kw)*NBK) + 2*np + sub)*BSZ + o];
  }
#pragma unroll
  for (int e = tid; e < 768; e += 384) {
    int sub = e / 384, r = e % 384, bb = r / 48, i = r % 48;
    int n = 2*np + sub;
    size_t ir = (((size_t)((bb*2 + 0)*64 + h)*33) + kw)*384 + n*48 + i;
    size_t ii = (((size_t)((bb*2 + 1)*64 + h)*33) + kw)*384 + n*48 + i;
    xl[sub][bb][i] = make_float2(b2fl(S2[ir]), b2fl(S2[ii]));
  }
  __syncthreads();
  int sub = tid / 192, r = tid % 192, bb = r / 24, o2 = r % 24;
  float4 bv = *(const float4*)(&bl[sub][2*o2]);
  float2 a0 = make_float2(bv.x, bv.y);
  float2 a1 = make_float2(bv.z, bv.w);
#pragma unroll
  for (int i = 0; i < 48; ++i) {
    float2 xv = xl[sub][bb][i];
    float4 wv = wl4[sub][i*24 + o2];
    a0.x += xv.x*wv.x - xv.y*wv.y;
    a0.y += xv.x*wv.y + xv.y*wv.x;
    a1.x += xv.x*wv.z - xv.y*wv.w;
    a1.y += xv.x*wv.w + xv.y*wv.z;
  }
  int n = 2*np + sub;
  size_t idr = (((size_t)((bb*2 + 0)*33) + kw)*64 + h)*384 + n*48 + 2*o2;
  size_t idi = (((size_t)((bb*2 + 1)*33) + kw)*64 + h)*384 + n*48 + 2*o2;
  *(unsigned*)(o1 + idr) = f2b(fmaxf(a0.x, 0.f)) | ((unsigned)f2b(fmaxf(a1.x, 0.f)) << 16);
  *(unsigned*)(o1 + idi) = f2b(fmaxf(a0.y, 0.f)) | ((unsigned)f2b(fmaxf(a1.y, 0.f)) << 16);
}

// ---------------- LN2 stats: per-token (mu, rs) from xsb ------------------------
__global__ __launch_bounds__(256) void stats_kernel(const unsigned short* __restrict__ in,
    float2* __restrict__ stats) {
  int token = blockIdx.x * 4 + (threadIdx.x >> 6);
  int lane = threadIdx.x & 63;
  const unsigned short* row = in + (size_t)token * CC;
  float s = 0.f, s2 = 0.f;
#pragma unroll
  for (int j = 0; j < 6; ++j) {
    float v = b2fl(row[lane + 64*j]);
    s += v; s2 += v*v;
  }
#pragma unroll
  for (int off = 32; off >= 1; off >>= 1) {
    s += __shfl_xor(s, off);
    s2 += __shfl_xor(s2, off);
  }
  if (lane == 0) {
    float mu = s * (1.0f/CC);
    float rs = rsqrtf(s2 * (1.0f/CC) - mu*mu + 1e-5f);
    stats[token] = make_float2(mu, rs);
  }
}

// ---------------- bf16 MFMA GEMM, BK=32 double-buffered 2-phase ----------------
// MODE 0: v = rs*(acc) - rs*mu*gs[n] + bb[n]; gelu; bf16 store (GEMM1, LN2 folded)
// MODE 1: out = acc + xs(bf16) + x + b2, fp32 (GEMM2, residual fused)
template<int MODE>
__global__ __launch_bounds__(256) void mfma_gemm_kernel(
    const unsigned short* __restrict__ A, int lda,
    const unsigned short* __restrict__ BT, int ldbt,
    void* __restrict__ Cp, int ldc, int K, int ntn,
    const float2* __restrict__ stats, const float2* __restrict__ gsbb,
    const unsigned short* __restrict__ xsb, const float* __restrict__ xres,
    const float* __restrict__ b2v) {
  __shared__ __align__(16) char gsm[32768];  // 2 bufs x (A 8KB + B 8KB)
  // XCD-aware bijective swizzle (grid % 8 == 0)
  int nb = (int)gridDim.x;
  int bidx = (int)blockIdx.x;
  int bswz = (bidx & 7) * (nb >> 3) + (bidx >> 3);
  int bn = bswz % ntn;
  int bm = bswz / ntn;
  int t = threadIdx.x;
  int lane = t & 63;
  int wid = t >> 6;
  int wm = wid >> 1, wn = wid & 1;
  int rr = lane & 15, rq = lane >> 4;

  f32x4 acc[4][4];
#pragma unroll
  for (int m = 0; m < 4; ++m)
#pragma unroll
    for (int n = 0; n < 4; ++n) acc[m][n] = (f32x4){0.f,0.f,0.f,0.f};

  const unsigned short* Abase = A + (size_t)bm*128*lda;
  const unsigned short* Bbase = BT + (size_t)bn*128*ldbt;
  int nt = K >> 5;

#define STG(bsel, t0)                                                        \
  {                                                                          \
    _Pragma("unroll")                                                        \
    for (int i = 0; i < 2; ++i) {                                            \
      int u = t + i*256;                                                     \
      int row = u >> 2, ch = u & 3;                                          \
      gload16(Abase + (size_t)row*lda + (t0)*32 + ((ch ^ (row & 3)) << 3),   \
              gsm + (bsel)*16384 + i*4096 + wid*1024);                       \
      gload16(Bbase + (size_t)row*ldbt + (t0)*32 + ((ch ^ (row & 3)) << 3),  \
              gsm + (bsel)*16384 + 8192 + i*4096 + wid*1024);                \
    }                                                                        \
  }

#define CMP(bsel)                                                            \
  {                                                                          \
    const char* Ab2 = gsm + (bsel)*16384;                                    \
    const char* Bb2 = Ab2 + 8192;                                            \
    bf16x8 af[4], bfv[4];                                                    \
    _Pragma("unroll")                                                        \
    for (int m = 0; m < 4; ++m) {                                            \
      int row = wm*64 + m*16 + rr;                                           \
      af[m] = *(const bf16x8*)(Ab2 + row*64 + ((rq ^ (row & 3)) << 4));      \
    }                                                                        \
    _Pragma("unroll")                                                        \
    for (int n = 0; n < 4; ++n) {                                            \
      int row = wn*64 + n*16 + rr;                                           \
      bfv[n] = *(const bf16x8*)(Bb2 + row*64 + ((rq ^ (row & 3)) << 4));     \
    }                                                                        \
    _Pragma("unroll")                                                        \
    for (int m = 0; m < 4; ++m)                                              \
      _Pragma("unroll")                                                      \
      for (int n = 0; n < 4; ++n)                                            \
        acc[m][n] = __builtin_amdgcn_mfma_f32_16x16x32_bf16(af[m], bfv[n], acc[m][n], 0, 0, 0); \
  }

  // T3 minimum 2-phase: issue STAGE(t+1) before COMPUTE(t); one barrier/tile
  STG(0, 0);
  __syncthreads();
  int cur = 0;
  for (int tt = 0; tt < nt - 1; ++tt) {
    STG(cur ^ 1, tt + 1);
    CMP(cur);
    __syncthreads();
    cur ^= 1;
  }
  CMP(cur);
  __syncthreads();

#undef STG
#undef CMP

  if (MODE == 0) {
    // LN2-affine + GELU, bf16 store via LDS repack
    unsigned short* ep = (unsigned short*)gsm;
#pragma unroll
    for (int m = 0; m < 4; ++m) {
      float2 st[4];
#pragma unroll
      for (int j = 0; j < 4; ++j)
        st[j] = stats[bm*128 + wm*64 + m*16 + rq*4 + j];
#pragma unroll
      for (int n = 0; n < 4; ++n) {
        int lcol = wn*64 + n*16 + rr;
        float2 gb = gsbb[bn*128 + lcol];
#pragma unroll
        for (int j = 0; j < 4; ++j) {
          float v = st[j].y * acc[m][n][j] - st[j].y * st[j].x * gb.x + gb.y;
          v = 0.5f*v*(1.f + erff(v*0.70710678118654752f));
          int row = wm*64 + m*16 + rq*4 + j;
          ep[row*128 + (lcol ^ ((row & 7) << 3))] = f2b(v);
        }
      }
    }
    __syncthreads();
    for (int it = t; it < 128*16; it += 256) {
      int m = it >> 4, u8 = it & 15;
      uint4 pw = *(const uint4*)(ep + m*128 + ((u8*8) ^ ((m & 7) << 3)));
      *(uint4*)((unsigned short*)Cp + (size_t)(bm*128 + m)*ldc + bn*128 + u8*8) = pw;
    }
  } else {
    // out = acc + xs(bf16) + x + b2, fp32, via 2-half LDS repack
    float* ep = (float*)gsm;  // 32 KB = 64*128 fp32
#pragma unroll
    for (int half = 0; half < 2; ++half) {
      __syncthreads();
#pragma unroll
      for (int mo = 0; mo < 2; ++mo) {
        int m = half*2 + mo;
#pragma unroll
        for (int n = 0; n < 4; ++n)
#pragma unroll
          for (int j = 0; j < 4; ++j) {
            int lr = wm*32 + mo*16 + rq*4 + j;
            int col = wn*64 + n*16 + rr;
            ep[lr*128 + (col ^ ((lr & 7) << 2))] = acc[m][n][j];
          }
      }
      __syncthreads();
      for (int it = t; it < 64*32; it += 256) {
        int lr = it >> 5, u = it & 31;
        int swz = (lr & 7) << 2;
        float4 v = *(const float4*)(ep + lr*128 + ((u*4) ^ swz));
        int grow = bm*128 + (lr >> 5)*64 + (half*2 + ((lr >> 4) & 1))*16 + (lr & 15);
        int gcol = bn*128 + u*4;
        size_t idx = (size_t)grow*ldc + gcol;
        float4 xr = *(const float4*)(xres + idx);
        uint2 xsv = *(const uint2*)(xsb + idx);
        float4 bv = *(const float4*)(b2v + gcol);
        float4 ov;
        ov.x = v.x + xr.x + b2fl((unsigned short)(xsv.x & 0xffffu)) + bv.x;
        ov.y = v.y + xr.y + b2fl((unsigned short)(xsv.x >> 16)) + bv.y;
        ov.z = v.z + xr.z + b2fl((unsigned short)(xsv.y & 0xffffu)) + bv.z;
        ov.w = v.w + xr.w + b2fl((unsigned short)(xsv.y >> 16)) + bv.w;
        *(float4*)((float*)Cp + idx) = ov;
      }
    }
  }
}

extern "C" void kernel_launch(void* const* d_in, const int* in_sizes, int n_in,
                              void* d_out, int out_size, void* d_ws, size_t ws_size,
                              hipStream_t stream) {
  const float* x   = (const float*)d_in[0];
  const float* w1  = (const float*)d_in[1];
  const float* b1  = (const float*)d_in[2];
  const float* n1w = (const float*)d_in[3];
  const float* n1b = (const float*)d_in[4];
  const float* n2w = (const float*)d_in[5];
  const float* n2b = (const float*)d_in[6];
  const float* mw1 = (const float*)d_in[7];
  const float* mb1 = (const float*)d_in[8];
  const float* mw2 = (const float*)d_in[9];
  const float* mb2 = (const float*)d_in[10];
  float* out = (float*)d_out;

  char* ws = (char*)d_ws;
  const size_t MB = 1ull << 20;
  unsigned short* xn  = (unsigned short*)(ws + 0*MB);    // 25.2 MB [b,h,c,w]
  unsigned short* S1  = (unsigned short*)(ws + 26*MB);   // 26 [b,h,m66,c]
  unsigned short* S2  = (unsigned short*)(ws + 53*MB);   // 26 [b2cp,kh,kw,c]
  unsigned short* o1  = (unsigned short*)(ws + 80*MB);   // 26 [b2cp,kw,h,c]
  unsigned short* S3  = (unsigned short*)(ws + 107*MB);  // 25.2 [b,kp,h,c]
  unsigned short* xsb = (unsigned short*)(ws + 133*MB);  // 25.2 bf16 xs
  float2*         stats = (float2*)(ws + 159*MB);        // 256 KB (mu, rs)
  unsigned short* hid = (unsigned short*)(ws + 185*MB);  // 100.7 bf16
  unsigned short* w1t = (unsigned short*)(ws + 286*MB);
  unsigned short* w2t = (unsigned short*)(ws + 288*MB);
  unsigned short* atab = (unsigned short*)(ws + 290*MB);
  float2*         gsbb = (float2*)(ws + 292*MB);         // 12 KB (gs, bb)

  // prep: twiddle tables + weight convert/transpose (g-folded) + gs/bb vectors
  prep_kernel<<<1222, 256, 0, stream>>>(atab, mw1, w1t, mw2, w2t, n2w, n2b, mb1, gsbb);

  // LN1 + transpose -> bf16
  ln1t_kernel<<<512, 256, 0, stream>>>(x, n1w, n1b, xn);
  // W-fwd
  dft_kernel<0><<<512*3, 256, 0, stream>>>(atab, xn, S1);
  // H-fwd
  dft_kernel<1><<<264*3, 256, 0, stream>>>(atab, S1, S2);
  // block-diag complex matmul + ReLU (2 modes/block)
  blockmm2_kernel<<<64*WF*4, 384, 0, stream>>>(S2, w1, b1, o1);
  // H-inv
  dft_kernel<2><<<264*3, 256, 0, stream>>>(atab, o1, S3);
  // W-inv -> xs (bf16)
  dft_kernel<3><<<512*3, 256, 0, stream>>>(atab, S3, xsb);
  // LN2 stats (mu, rs per token)
  stats_kernel<<<NTOK/4, 256, 0, stream>>>(xsb, stats);
  // GEMM1: hid = gelu(LN2(xs) @ W1 + b1) via affine epilogue  M=32768 N=1536 K=384
  mfma_gemm_kernel<0><<<256*12, 256, 0, stream>>>(xsb, 384, w1t, 384,
                                                  hid, 1536, 384, 12,
                                                  stats, gsbb, nullptr, nullptr, nullptr);
  // GEMM2: out = hid @ W2 + xs + x + b2  M=32768 N=384 K=1536
  mfma_gemm_kernel<1><<<256*3, 256, 0, stream>>>(hid, 1536, w2t, 1536,
                                                 out, 384, 1536, 3,
                                                 nullptr, nullptr, xsb, x, mb2);
}